// Round 13
// baseline (171.857 us; speedup 1.0000x reference)
//
#include <hip/hip_runtime.h>
#include <hip/hip_bf16.h>

typedef __bf16 bf16;
typedef __bf16 bf16x2 __attribute__((ext_vector_type(2)));
typedef __bf16 bf16x4 __attribute__((ext_vector_type(4)));
typedef __bf16 bf16x8 __attribute__((ext_vector_type(8)));
typedef float  f32x4  __attribute__((ext_vector_type(4)));
typedef int    i32x2  __attribute__((ext_vector_type(2)));
typedef int    i32x4  __attribute__((ext_vector_type(4)));

#define NEG_INF (-1e9f)
#define N_SCENES 2048

#if defined(__has_builtin)
#if __has_builtin(__builtin_amdgcn_exp2f)
#define EXP2(x) __builtin_amdgcn_exp2f(x)
#endif
#endif
#ifndef EXP2
#define EXP2(x) exp2f(x)
#endif

#define PRIO_HI() __builtin_amdgcn_s_setprio(1)
#define PRIO_LO() __builtin_amdgcn_s_setprio(0)

// v_permlane32_swap_b32: a' = {a.lo32lanes, b.lo32lanes}, b' = {a.hi, b.hi}
static __device__ __forceinline__ void pl32(int& a, int& b) {
#if defined(__has_builtin) && __has_builtin(__builtin_amdgcn_permlane32_swap)
    i32x2 res = __builtin_amdgcn_permlane32_swap(a, b, false, false);
    a = res[0]; b = res[1];
#else
    asm("v_permlane32_swap_b32 %0, %1" : "+v"(a), "+v"(b));
#endif
}

// xor-32 reduction step via permlane32_swap (1 VALU op vs ds_bpermute):
// after pl32(a,b=a): lane i<32 holds {x[i], x[i+32]}, lane i>=32 {x[i-32], x[i]}.
static __device__ __forceinline__ float xsw32_max(float x) {
    int a = __builtin_bit_cast(int, x), b = a;
    pl32(a, b);
    return fmaxf(__builtin_bit_cast(float, a), __builtin_bit_cast(float, b));
}
static __device__ __forceinline__ float xsw32_add(float x) {
    int a = __builtin_bit_cast(int, x), b = a;
    pl32(a, b);
    return __builtin_bit_cast(float, a) + __builtin_bit_cast(float, b);
}

// pack two f32 -> one dword of 2 bf16 (compiler emits v_cvt_pk_bf16_f32)
static __device__ __forceinline__ int pk2(float x, float y) {
    bf16x2 t = {(bf16)x, (bf16)y};
    return __builtin_bit_cast(int, t);
}

// Quad-transpose transform (replaces the 16-bpermute quad-shuffle):
// sources a0,a1 (tile A words), b0,b1 (tile B words), each word = 2 bf16.
// Source layout: lane(r,qd') word w of tile T = elems [T*16 + qd'*4 + 2w, +1].
// Target: word j at lane(r,qd) = elems [qd*8 + 2j, +1] (A for qd<2, B else).
static __device__ __forceinline__ i32x4 qtrans(int a0, int a1, int b0, int b1,
                                               bool qodd) {
    i32x4 out;
    pl32(a0, b0);                       // a0={A.lo,B.lo}  b0={A.hi,B.hi}
    int y2 = __shfl_xor(b0, 16);
    int x2 = __shfl_xor(a0, 16);
    out[0] = qodd ? y2 : a0;
    out[2] = qodd ? b0 : x2;
    pl32(a1, b1);
    int y2b = __shfl_xor(b1, 16);
    int x2b = __shfl_xor(a1, 16);
    out[1] = qodd ? y2b : a1;
    out[3] = qodd ? b1 : x2b;
    return out;
}

// ---------------------------------------------------------------------------
// Prep: block 0: exclusive prefix sum of agents (B=2048); blocks 1..64:
// fp32 -> bf16 weight conversion into workspace.
// ---------------------------------------------------------------------------
__global__ __launch_bounds__(256) void prep_kernel(
    const float* __restrict__ w_in, const float* __restrict__ w_out,
    const int* __restrict__ agents,
    bf16* __restrict__ w_in_b, bf16* __restrict__ w_out_b, int* __restrict__ offs)
{
    __shared__ int tot[256];
    const int t = threadIdx.x;
    if (blockIdx.x == 0) {
        int loc[8]; int s = 0;
        #pragma unroll
        for (int j = 0; j < 8; ++j) { loc[j] = agents[t * 8 + j]; s += loc[j]; }
        tot[t] = s;
        __syncthreads();
        for (int o = 1; o < 256; o <<= 1) {
            int v = (t >= o) ? tot[t - o] : 0;
            __syncthreads();
            tot[t] += v;
            __syncthreads();
        }
        int run = tot[t] - s;
        #pragma unroll
        for (int j = 0; j < 8; ++j) { offs[t * 8 + j] = run; run += loc[j]; }
    } else {
        int i = (blockIdx.x - 1) * 1024 + t * 4;
        float4 v; bf16* dst;
        if (i < 49152) { v = *(const float4*)(w_in + i);            dst = w_in_b + i; }
        else           { v = *(const float4*)(w_out + (i - 49152)); dst = w_out_b + (i - 49152); }
        bf16x4 o = { (bf16)v.x, (bf16)v.y, (bf16)v.z, (bf16)v.w };
        *(bf16x4*)dst = o;
    }
}

// ---------------------------------------------------------------------------
// R17: R16 (clean R7 body + setprio, attn 75.3us -- best verified) + ONE
// zero-register-pressure delta: the softmax's two xor-32 reduce steps
// (max and sum) use v_permlane32_swap (1 VALU op) instead of __shfl_xor's
// ds_bpermute (~40-120cy DS latency, serial on the softmax critical path).
// Scalar-float substitution only -- no layout/packing/array-type changes
// (the R14 spill trigger was repacking the xa arrays; R14 lesson: this
// allocator demotes to scratch on IR perturbations -- detector: FETCH >
// 20MB or WRITE > 70MB means spill, revert to R16).
// Structure: 4 waves, wave=head, Q in regs, K/V via 32KB LDS (swizzled),
// qtrans quad-transposes for qf/P^T/ctx^T, ctxS overlays Kld, log2-domain
// softmax, setprio(1) around MFMA clusters.
// MFMA 16x16x32_bf16: A[m=lane&15][k=quad*8+jj], B[k=quad*8+jj][n=lane&15],
// C/D: col=lane&15, row=quad*4+reg.
// ---------------------------------------------------------------------------
__global__ __launch_bounds__(256, 4) void attn_kernel(
    const float* __restrict__ att_in,
    const float* __restrict__ b_in, const float* __restrict__ b_out,
    const bf16* __restrict__ w_in_b, const bf16* __restrict__ w_out_b,
    const int* __restrict__ agents, const int* __restrict__ offs,
    float* __restrict__ out)
{
    __shared__ bf16 s_lds[4 * 4096];   // 32 KB

    const int b    = blockIdx.x;
    const int tid  = threadIdx.x;
    const int lane = tid & 63;
    const int w    = tid >> 6;         // wave id == head id
    const int h    = w;
    const int r    = lane & 15;
    const int qd   = lane >> 4;        // quad 0..3
    const int q1   = qd & 1;
    const int qh   = qd >> 1;
    const bool qodd = (q1 != 0);
    const int nb   = agents[b];
    const int off  = offs[b];
    const int mtc  = (nb + 15) >> 4;   // live m-tiles (1..4)

    bf16* Kld = s_lds + h * 4096;      // K[64][32] swizzled; later ctxS[4mt][64][8]
    bf16* vT  = Kld + 2048;            // vT[32][64]

    // ---- zero-fill output rows [nb, 64) ----
    {
        const float4 z4 = make_float4(0.f, 0.f, 0.f, 0.f);
        const int nz = (64 - nb) * 32;
        for (int i = tid; i < nz; i += 256) {
            int row = nb + (i >> 5);
            *(float4*)(out + ((size_t)b * 64 + row) * 128 + (i & 31) * 4) = z4;
        }
    }

    // ---- zero vT units for agents >= mtc*16 (keep PV inputs finite) ----
    {
        bf16x4 z4 = {(bf16)0.f,(bf16)0.f,(bf16)0.f,(bf16)0.f};
        int zrow = lane >> 1, zh = lane & 1;     // 32 rows x 2 halves
        #pragma unroll
        for (int un = 2; un < 8; ++un)
            if (un >= 2 * mtc) {
                int uu = un ^ (zrow & 7);
                *(bf16x4*)(vT + zrow * 64 + uu * 8 + zh * 4) = z4;
            }
    }

    // ---- x fragments from global (rows >= nb -> 0); serve as A and B ----
    bf16x8 xa[4][4];
    #pragma unroll
    for (int mt = 0; mt < 4; ++mt) {
        const int xrow = mt * 16 + r;
        const bool vr = xrow < nb;
        const float* px = att_in + (((size_t)(off + xrow)) << 7) + qd * 8;
        #pragma unroll
        for (int ks = 0; ks < 4; ++ks) {
            float4 lo = make_float4(0.f,0.f,0.f,0.f), hi = lo;
            if (vr) {
                lo = *(const float4*)(px + ks * 32);
                hi = *(const float4*)(px + ks * 32 + 4);
            }
            xa[mt][ks] = (bf16x8){(bf16)lo.x,(bf16)lo.y,(bf16)lo.z,(bf16)lo.w,
                                  (bf16)hi.x,(bf16)hi.y,(bf16)hi.z,(bf16)hi.w};
        }
    }

    // ---- stage 1a: Q tiles -> registers (packed with bias) ----
    // qreg[mt][jt] at lane(r,qd) = Q[agent=mt*16+r][d = jt*16+qd*4+reg]+bias
    bf16x4 qreg[4][2];
    #pragma unroll
    for (int jt = 0; jt < 2; ++jt) {
        const int j0 = h * 32 + jt * 16;
        const bf16* pw = w_in_b + (size_t)(j0 + r) * 128 + qd * 8;
        bf16x8 wb[4];
        #pragma unroll
        for (int ks = 0; ks < 4; ++ks)
            wb[ks] = *(const bf16x8*)(pw + ks * 32);
        const float4 b4 = *(const float4*)(b_in + j0 + qd * 4);
        PRIO_HI();
        #pragma unroll
        for (int mt = 0; mt < 4; ++mt)
            if (mt < mtc) {
                f32x4 acc = {0.f,0.f,0.f,0.f};
                #pragma unroll
                for (int ks = 0; ks < 4; ++ks)
                    acc = __builtin_amdgcn_mfma_f32_16x16x32_bf16(wb[ks], xa[mt][ks], acc, 0, 0, 0);
                qreg[mt][jt] = (bf16x4){(bf16)(acc[0]+b4.x), (bf16)(acc[1]+b4.y),
                                        (bf16)(acc[2]+b4.z), (bf16)(acc[3]+b4.w)};
            }
        PRIO_LO();
    }

    // ---- stage 1b: K tiles -> LDS (swizzled, as R4) ----
    #pragma unroll
    for (int jt = 0; jt < 2; ++jt) {
        const int j0 = 128 + h * 32 + jt * 16;
        const bf16* pw = w_in_b + (size_t)(j0 + r) * 128 + qd * 8;
        bf16x8 wb[4];
        #pragma unroll
        for (int ks = 0; ks < 4; ++ks)
            wb[ks] = *(const bf16x8*)(pw + ks * 32);
        const float4 b4 = *(const float4*)(b_in + j0 + qd * 4);
        PRIO_HI();
        #pragma unroll
        for (int mt = 0; mt < 4; ++mt)
            if (mt < mtc) {
                f32x4 acc = {0.f,0.f,0.f,0.f};
                #pragma unroll
                for (int ks = 0; ks < 4; ++ks)
                    acc = __builtin_amdgcn_mfma_f32_16x16x32_bf16(wb[ks], xa[mt][ks], acc, 0, 0, 0);
                bf16x4 pk = {(bf16)(acc[0]+b4.x), (bf16)(acc[1]+b4.y),
                             (bf16)(acc[2]+b4.z), (bf16)(acc[3]+b4.w)};
                int rowa = mt * 16 + r;
                int uu = (jt * 2 + qh) ^ (rowa & 3);
                *(bf16x4*)(Kld + rowa * 32 + uu * 8 + q1 * 4) = pk;
            }
        PRIO_LO();
    }

    // ---- stage 1c: V tiles -> LDS transposed (as R4) ----
    #pragma unroll
    for (int jt = 0; jt < 2; ++jt) {
        const int j0 = 256 + h * 32 + jt * 16;
        const bf16* pw = w_in_b + (size_t)(j0 + r) * 128 + qd * 8;
        bf16x8 wb[4];
        #pragma unroll
        for (int ks = 0; ks < 4; ++ks)
            wb[ks] = *(const bf16x8*)(pw + ks * 32);
        const float bv = b_in[j0 + r];
        PRIO_HI();
        #pragma unroll
        for (int mt = 0; mt < 4; ++mt)
            if (mt < mtc) {
                f32x4 acc = {0.f,0.f,0.f,0.f};
                #pragma unroll
                for (int ks = 0; ks < 4; ++ks)
                    acc = __builtin_amdgcn_mfma_f32_16x16x32_bf16(xa[mt][ks], wb[ks], acc, 0, 0, 0);
                bf16x4 pk = {(bf16)(acc[0]+bv), (bf16)(acc[1]+bv),
                             (bf16)(acc[2]+bv), (bf16)(acc[3]+bv)};
                int rowd = jt * 16 + r;
                int uu = (mt * 2 + qh) ^ (rowd & 7);
                *(bf16x4*)(vT + rowd * 64 + uu * 8 + q1 * 4) = pk;
            }
        PRIO_LO();
    }

    // ---- stage 2 preloads: K A-frags, V^T A-frags (wave-local LDS) ----
    bf16x8 kf[4];
    #pragma unroll
    for (int nt = 0; nt < 4; ++nt)
        if (nt < mtc) {
            int row = nt * 16 + r;
            kf[nt] = *(const bf16x8*)(Kld + row * 32 + (qd ^ (row & 3)) * 8);
        }
    bf16x8 vf[2][2];
    #pragma unroll
    for (int dt = 0; dt < 2; ++dt)
        #pragma unroll
        for (int hk = 0; hk < 2; ++hk) {
            int row = dt * 16 + r;
            vf[dt][hk] = *(const bf16x8*)(vT + row * 64 + ((hk * 4 + qd) ^ (row & 7)) * 8);
        }
    bf16x8 wof[2][4]; float4 bo4[2];
    #pragma unroll
    for (int t2 = 0; t2 < 2; ++t2) {
        const int jg = (h * 2 + t2) * 16;
        const bf16* pw = w_out_b + (size_t)(jg + r) * 128 + qd * 8;
        #pragma unroll
        for (int s = 0; s < 4; ++s)
            wof[t2][s] = *(const bf16x8*)(pw + s * 32);
        bo4[t2] = *(const float4*)(b_out + jg + qd * 4);
    }

    const float k1 = 0.25503484f;      // (1/sqrt(32)) * log2(e)

    // ---- stage 2: per query-tile mt: S^T -> softmax -> P^T -> PV ----
    #pragma unroll
    for (int mt = 0; mt < 4; ++mt)
        if (mt < mtc) {
            // qf = B-frag Q[agent=r][d=qd*8+jj] from qreg via quad-transform
            i32x2 qa = __builtin_bit_cast(i32x2, qreg[mt][0]);
            i32x2 qb = __builtin_bit_cast(i32x2, qreg[mt][1]);
            i32x4 qw = qtrans(qa[0], qa[1], qb[0], qb[1], qodd);
            bf16x8 qf = __builtin_bit_cast(bf16x8, qw);

            f32x4 S[4];
            PRIO_HI();
            #pragma unroll
            for (int nt = 0; nt < 4; ++nt)
                if (nt < mtc) {
                    f32x4 z = {0.f,0.f,0.f,0.f};
                    S[nt] = __builtin_amdgcn_mfma_f32_16x16x32_bf16(kf[nt], qf, z, 0, 0, 0);
                }
            PRIO_LO();
            // masked softmax (log2 domain) over keys n = nt*16 + qd*4 + i
            #pragma unroll
            for (int nt = 0; nt < 4; ++nt) {
                if (nt < mtc) {
                    #pragma unroll
                    for (int i = 0; i < 4; ++i) {
                        bool kv = (nt * 16 + qd * 4 + i) < nb;
                        S[nt][i] = kv ? S[nt][i] * k1 : NEG_INF;
                    }
                } else {
                    S[nt] = (f32x4){NEG_INF, NEG_INF, NEG_INF, NEG_INF};
                }
            }
            float tm[4];
            #pragma unroll
            for (int nt = 0; nt < 4; ++nt)
                tm[nt] = fmaxf(fmaxf(S[nt][0], S[nt][1]), fmaxf(S[nt][2], S[nt][3]));
            float mx = fmaxf(fmaxf(tm[0], tm[1]), fmaxf(tm[2], tm[3]));
            mx = fmaxf(mx, __shfl_xor(mx, 16));
            mx = xsw32_max(mx);
            float lt[4];
            #pragma unroll
            for (int nt = 0; nt < 4; ++nt) {
                float e0 = EXP2(S[nt][0] - mx), e1 = EXP2(S[nt][1] - mx);
                float e2 = EXP2(S[nt][2] - mx), e3 = EXP2(S[nt][3] - mx);
                S[nt][0] = e0; S[nt][1] = e1; S[nt][2] = e2; S[nt][3] = e3;
                lt[nt] = (e0 + e1) + (e2 + e3);
            }
            float l = (lt[0] + lt[1]) + (lt[2] + lt[3]);
            l += __shfl_xor(l, 16);
            l = xsw32_add(l);
            const float rl = 1.0f / l;
            #pragma unroll
            for (int nt = 0; nt < 4; ++nt)
                #pragma unroll
                for (int i = 0; i < 4; ++i)
                    S[nt][i] *= rl;                       // invalid keys -> exact 0

            // PV: O^T = V^T * P^T ; P^T frags via quad-transform (no bpermute)
            f32x4 o0 = {0.f,0.f,0.f,0.f}, o1 = {0.f,0.f,0.f,0.f};
            #pragma unroll
            for (int hk = 0; hk < 2; ++hk)
                if (hk * 2 < mtc) {
                    int a0 = pk2(S[2*hk  ][0], S[2*hk  ][1]);
                    int a1 = pk2(S[2*hk  ][2], S[2*hk  ][3]);
                    int b0 = pk2(S[2*hk+1][0], S[2*hk+1][1]);
                    int b1 = pk2(S[2*hk+1][2], S[2*hk+1][3]);
                    i32x4 pw4 = qtrans(a0, a1, b0, b1, qodd);
                    bf16x8 pf = __builtin_bit_cast(bf16x8, pw4);
                    PRIO_HI();
                    o0 = __builtin_amdgcn_mfma_f32_16x16x32_bf16(vf[0][hk], pf, o0, 0, 0, 0);
                    o1 = __builtin_amdgcn_mfma_f32_16x16x32_bf16(vf[1][hk], pf, o1, 0, 0, 0);
                    PRIO_LO();
                }

            // ctx^T B-frag via quad-transform -> one b128 LDS write (ctxS
            // overlays K; kf already register-resident; wave-local region)
            {
                int a0 = pk2(o0[0], o0[1]);
                int a1 = pk2(o0[2], o0[3]);
                int b0 = pk2(o1[0], o1[1]);
                int b1 = pk2(o1[2], o1[3]);
                i32x4 cw = qtrans(a0, a1, b0, b1, qodd);
                bf16x8 cf = __builtin_bit_cast(bf16x8, cw);
                *(bf16x8*)(Kld + mt * 512 + lane * 8) = cf;   // ctxS[h][mt][lane]
            }
        }
    __syncthreads();

    // ---- stage 3: out^T = W_out * ctx^T ; float4 stores ----
    #pragma unroll
    for (int mt = 0; mt < 4; ++mt)
        if (mt < mtc) {
            bf16x8 cb[4];
            #pragma unroll
            for (int s = 0; s < 4; ++s)
                cb[s] = *(const bf16x8*)(s_lds + s * 4096 + mt * 512 + lane * 8);
            const int rowa = mt * 16 + r;
            PRIO_HI();
            #pragma unroll
            for (int t2 = 0; t2 < 2; ++t2) {
                f32x4 acc = {0.f,0.f,0.f,0.f};
                #pragma unroll
                for (int s = 0; s < 4; ++s)
                    acc = __builtin_amdgcn_mfma_f32_16x16x32_bf16(wof[t2][s], cb[s], acc, 0, 0, 0);
                if (rowa < nb) {
                    float4 o4 = make_float4(acc[0] + bo4[t2].x, acc[1] + bo4[t2].y,
                                            acc[2] + bo4[t2].z, acc[3] + bo4[t2].w);
                    *(float4*)(out + ((size_t)b * 64 + rowa) * 128
                               + (w * 2 + t2) * 16 + qd * 4) = o4;
                }
            }
            PRIO_LO();
        }
}

extern "C" void kernel_launch(void* const* d_in, const int* in_sizes, int n_in,
                              void* d_out, int out_size, void* d_ws, size_t ws_size,
                              hipStream_t stream)
{
    const float* att_in = (const float*)d_in[0];
    const float* w_in   = (const float*)d_in[1];
    const float* b_in   = (const float*)d_in[2];
    const float* w_out  = (const float*)d_in[3];
    const float* b_out  = (const float*)d_in[4];
    const int*   agents = (const int*)d_in[5];

    bf16* w_in_b  = (bf16*)d_ws;                         // 49152 * 2B
    bf16* w_out_b = w_in_b + 49152;                      // 16384 * 2B
    int*  offs    = (int*)((char*)d_ws + 98304 + 32768); // 2048 * 4B

    prep_kernel<<<65, 256, 0, stream>>>(w_in, w_out, agents, w_in_b, w_out_b, offs);
    attn_kernel<<<N_SCENES, 256, 0, stream>>>(att_in, b_in, b_out, w_in_b, w_out_b,
                                              agents, offs, (float*)d_out);
}

// Round 14
// 167.727 us; speedup vs baseline: 1.0246x; 1.0246x over previous
//
#include <hip/hip_runtime.h>
#include <hip/hip_bf16.h>

typedef __bf16 bf16;
typedef __bf16 bf16x2 __attribute__((ext_vector_type(2)));
typedef __bf16 bf16x4 __attribute__((ext_vector_type(4)));
typedef __bf16 bf16x8 __attribute__((ext_vector_type(8)));
typedef float  f32x4  __attribute__((ext_vector_type(4)));
typedef int    i32x2  __attribute__((ext_vector_type(2)));
typedef int    i32x4  __attribute__((ext_vector_type(4)));

#define NEG_INF (-1e9f)
#define N_SCENES 2048

#if defined(__has_builtin)
#if __has_builtin(__builtin_amdgcn_exp2f)
#define EXP2(x) __builtin_amdgcn_exp2f(x)
#endif
#endif
#ifndef EXP2
#define EXP2(x) exp2f(x)
#endif

#define PRIO_HI() __builtin_amdgcn_s_setprio(1)
#define PRIO_LO() __builtin_amdgcn_s_setprio(0)

// v_permlane32_swap_b32: a' = {a.lo32lanes, b.lo32lanes}, b' = {a.hi, b.hi}
static __device__ __forceinline__ void pl32(int& a, int& b) {
#if defined(__has_builtin) && __has_builtin(__builtin_amdgcn_permlane32_swap)
    i32x2 res = __builtin_amdgcn_permlane32_swap(a, b, false, false);
    a = res[0]; b = res[1];
#else
    asm("v_permlane32_swap_b32 %0, %1" : "+v"(a), "+v"(b));
#endif
}

// pack two f32 -> one dword of 2 bf16 (compiler emits v_cvt_pk_bf16_f32)
static __device__ __forceinline__ int pk2(float x, float y) {
    bf16x2 t = {(bf16)x, (bf16)y};
    return __builtin_bit_cast(int, t);
}

// Quad-transpose transform (replaces the 16-bpermute quad-shuffle):
// sources a0,a1 (tile A words), b0,b1 (tile B words), each word = 2 bf16.
// Source layout: lane(r,qd') word w of tile T = elems [T*16 + qd'*4 + 2w, +1].
// Target: word j at lane(r,qd) = elems [qd*8 + 2j, +1] (A for qd<2, B else).
static __device__ __forceinline__ i32x4 qtrans(int a0, int a1, int b0, int b1,
                                               bool qodd) {
    i32x4 out;
    pl32(a0, b0);                       // a0={A.lo,B.lo}  b0={A.hi,B.hi}
    int y2 = __shfl_xor(b0, 16);
    int x2 = __shfl_xor(a0, 16);
    out[0] = qodd ? y2 : a0;
    out[2] = qodd ? b0 : x2;
    pl32(a1, b1);
    int y2b = __shfl_xor(b1, 16);
    int x2b = __shfl_xor(a1, 16);
    out[1] = qodd ? y2b : a1;
    out[3] = qodd ? b1 : x2b;
    return out;
}

// ---------------------------------------------------------------------------
// Prep: block 0: exclusive prefix sum of agents (B=2048) + LPT permutation
// (counting sort by descending nb -> heavy scenes dispatch first);
// blocks 1..64: fp32 -> bf16 weight conversion into workspace.
// ---------------------------------------------------------------------------
__global__ __launch_bounds__(256) void prep_kernel(
    const float* __restrict__ w_in, const float* __restrict__ w_out,
    const int* __restrict__ agents,
    bf16* __restrict__ w_in_b, bf16* __restrict__ w_out_b,
    int* __restrict__ offs, int* __restrict__ perm)
{
    __shared__ int tot[256];
    __shared__ int hist[64];
    __shared__ int base[64];
    const int t = threadIdx.x;
    if (blockIdx.x == 0) {
        int loc[8]; int s = 0;
        #pragma unroll
        for (int j = 0; j < 8; ++j) { loc[j] = agents[t * 8 + j]; s += loc[j]; }
        tot[t] = s;
        if (t < 64) hist[t] = 0;
        __syncthreads();
        for (int o = 1; o < 256; o <<= 1) {
            int v = (t >= o) ? tot[t - o] : 0;
            __syncthreads();
            tot[t] += v;
            __syncthreads();
        }
        int run = tot[t] - s;
        #pragma unroll
        for (int j = 0; j < 8; ++j) { offs[t * 8 + j] = run; run += loc[j]; }

        if (perm) {
            // counting sort, key k = 64 - nb (0..63): descending nb order
            #pragma unroll
            for (int j = 0; j < 8; ++j)
                atomicAdd(&hist[64 - loc[j]], 1);
            __syncthreads();
            if (t < 64) base[t] = hist[t];
            __syncthreads();
            for (int o = 1; o < 64; o <<= 1) {
                int v = (t >= o && t < 64) ? base[t - o] : 0;
                __syncthreads();
                if (t < 64) base[t] += v;
                __syncthreads();
            }
            if (t < 64) hist[t] = base[t] - hist[t];   // exclusive bucket start
            __syncthreads();
            #pragma unroll
            for (int j = 0; j < 8; ++j) {
                int rank = atomicAdd(&hist[64 - loc[j]], 1);
                perm[rank] = t * 8 + j;
            }
        }
    } else {
        int i = (blockIdx.x - 1) * 1024 + t * 4;
        float4 v; bf16* dst;
        if (i < 49152) { v = *(const float4*)(w_in + i);            dst = w_in_b + i; }
        else           { v = *(const float4*)(w_out + (i - 49152)); dst = w_out_b + (i - 49152); }
        bf16x4 o = { (bf16)v.x, (bf16)v.y, (bf16)v.z, (bf16)v.w };
        *(bf16x4*)dst = o;
    }
}

// ---------------------------------------------------------------------------
// R18: R16 (clean R7 body + setprio, attn 75.3us -- best verified; R17's
// permlane softmax reduce was neutral/slightly-negative and is reverted)
// + LPT dispatch: scenes processed in descending-nb order via a counting-
// sort permutation built in prep (blockIdx order ~ dispatch order, so
// heavy mtc=4 scenes start first and the tail is packed with cheap ones;
// scene work varies 4x). The ONLY attn change is one uniform scalar load
// b = perm[blockIdx.x] -- no vector-register/layout perturbation (R14
// lesson: spill triggers were vector-array repacking; detector: FETCH >
// 20MB or WRITE > 70MB means spill, revert to R16).
// Structure: 4 waves, wave=head, Q in regs, K/V via 32KB LDS (swizzled),
// qtrans quad-transposes for qf/P^T/ctx^T, ctxS overlays Kld, log2-domain
// softmax, setprio(1) around MFMA clusters.
// MFMA 16x16x32_bf16: A[m=lane&15][k=quad*8+jj], B[k=quad*8+jj][n=lane&15],
// C/D: col=lane&15, row=quad*4+reg.
// ---------------------------------------------------------------------------
__global__ __launch_bounds__(256, 4) void attn_kernel(
    const float* __restrict__ att_in,
    const float* __restrict__ b_in, const float* __restrict__ b_out,
    const bf16* __restrict__ w_in_b, const bf16* __restrict__ w_out_b,
    const int* __restrict__ agents, const int* __restrict__ offs,
    const int* __restrict__ perm,
    float* __restrict__ out)
{
    __shared__ bf16 s_lds[4 * 4096];   // 32 KB

    const int b    = perm ? perm[blockIdx.x] : blockIdx.x;
    const int tid  = threadIdx.x;
    const int lane = tid & 63;
    const int w    = tid >> 6;         // wave id == head id
    const int h    = w;
    const int r    = lane & 15;
    const int qd   = lane >> 4;        // quad 0..3
    const int q1   = qd & 1;
    const int qh   = qd >> 1;
    const bool qodd = (q1 != 0);
    const int nb   = agents[b];
    const int off  = offs[b];
    const int mtc  = (nb + 15) >> 4;   // live m-tiles (1..4)

    bf16* Kld = s_lds + h * 4096;      // K[64][32] swizzled; later ctxS[4mt][64][8]
    bf16* vT  = Kld + 2048;            // vT[32][64]

    // ---- zero-fill output rows [nb, 64) ----
    {
        const float4 z4 = make_float4(0.f, 0.f, 0.f, 0.f);
        const int nz = (64 - nb) * 32;
        for (int i = tid; i < nz; i += 256) {
            int row = nb + (i >> 5);
            *(float4*)(out + ((size_t)b * 64 + row) * 128 + (i & 31) * 4) = z4;
        }
    }

    // ---- zero vT units for agents >= mtc*16 (keep PV inputs finite) ----
    {
        bf16x4 z4 = {(bf16)0.f,(bf16)0.f,(bf16)0.f,(bf16)0.f};
        int zrow = lane >> 1, zh = lane & 1;     // 32 rows x 2 halves
        #pragma unroll
        for (int un = 2; un < 8; ++un)
            if (un >= 2 * mtc) {
                int uu = un ^ (zrow & 7);
                *(bf16x4*)(vT + zrow * 64 + uu * 8 + zh * 4) = z4;
            }
    }

    // ---- x fragments from global (rows >= nb -> 0); serve as A and B ----
    bf16x8 xa[4][4];
    #pragma unroll
    for (int mt = 0; mt < 4; ++mt) {
        const int xrow = mt * 16 + r;
        const bool vr = xrow < nb;
        const float* px = att_in + (((size_t)(off + xrow)) << 7) + qd * 8;
        #pragma unroll
        for (int ks = 0; ks < 4; ++ks) {
            float4 lo = make_float4(0.f,0.f,0.f,0.f), hi = lo;
            if (vr) {
                lo = *(const float4*)(px + ks * 32);
                hi = *(const float4*)(px + ks * 32 + 4);
            }
            xa[mt][ks] = (bf16x8){(bf16)lo.x,(bf16)lo.y,(bf16)lo.z,(bf16)lo.w,
                                  (bf16)hi.x,(bf16)hi.y,(bf16)hi.z,(bf16)hi.w};
        }
    }

    // ---- stage 1a: Q tiles -> registers (packed with bias) ----
    // qreg[mt][jt] at lane(r,qd) = Q[agent=mt*16+r][d = jt*16+qd*4+reg]+bias
    bf16x4 qreg[4][2];
    #pragma unroll
    for (int jt = 0; jt < 2; ++jt) {
        const int j0 = h * 32 + jt * 16;
        const bf16* pw = w_in_b + (size_t)(j0 + r) * 128 + qd * 8;
        bf16x8 wb[4];
        #pragma unroll
        for (int ks = 0; ks < 4; ++ks)
            wb[ks] = *(const bf16x8*)(pw + ks * 32);
        const float4 b4 = *(const float4*)(b_in + j0 + qd * 4);
        PRIO_HI();
        #pragma unroll
        for (int mt = 0; mt < 4; ++mt)
            if (mt < mtc) {
                f32x4 acc = {0.f,0.f,0.f,0.f};
                #pragma unroll
                for (int ks = 0; ks < 4; ++ks)
                    acc = __builtin_amdgcn_mfma_f32_16x16x32_bf16(wb[ks], xa[mt][ks], acc, 0, 0, 0);
                qreg[mt][jt] = (bf16x4){(bf16)(acc[0]+b4.x), (bf16)(acc[1]+b4.y),
                                        (bf16)(acc[2]+b4.z), (bf16)(acc[3]+b4.w)};
            }
        PRIO_LO();
    }

    // ---- stage 1b: K tiles -> LDS (swizzled, as R4) ----
    #pragma unroll
    for (int jt = 0; jt < 2; ++jt) {
        const int j0 = 128 + h * 32 + jt * 16;
        const bf16* pw = w_in_b + (size_t)(j0 + r) * 128 + qd * 8;
        bf16x8 wb[4];
        #pragma unroll
        for (int ks = 0; ks < 4; ++ks)
            wb[ks] = *(const bf16x8*)(pw + ks * 32);
        const float4 b4 = *(const float4*)(b_in + j0 + qd * 4);
        PRIO_HI();
        #pragma unroll
        for (int mt = 0; mt < 4; ++mt)
            if (mt < mtc) {
                f32x4 acc = {0.f,0.f,0.f,0.f};
                #pragma unroll
                for (int ks = 0; ks < 4; ++ks)
                    acc = __builtin_amdgcn_mfma_f32_16x16x32_bf16(wb[ks], xa[mt][ks], acc, 0, 0, 0);
                bf16x4 pk = {(bf16)(acc[0]+b4.x), (bf16)(acc[1]+b4.y),
                             (bf16)(acc[2]+b4.z), (bf16)(acc[3]+b4.w)};
                int rowa = mt * 16 + r;
                int uu = (jt * 2 + qh) ^ (rowa & 3);
                *(bf16x4*)(Kld + rowa * 32 + uu * 8 + q1 * 4) = pk;
            }
        PRIO_LO();
    }

    // ---- stage 1c: V tiles -> LDS transposed (as R4) ----
    #pragma unroll
    for (int jt = 0; jt < 2; ++jt) {
        const int j0 = 256 + h * 32 + jt * 16;
        const bf16* pw = w_in_b + (size_t)(j0 + r) * 128 + qd * 8;
        bf16x8 wb[4];
        #pragma unroll
        for (int ks = 0; ks < 4; ++ks)
            wb[ks] = *(const bf16x8*)(pw + ks * 32);
        const float bv = b_in[j0 + r];
        PRIO_HI();
        #pragma unroll
        for (int mt = 0; mt < 4; ++mt)
            if (mt < mtc) {
                f32x4 acc = {0.f,0.f,0.f,0.f};
                #pragma unroll
                for (int ks = 0; ks < 4; ++ks)
                    acc = __builtin_amdgcn_mfma_f32_16x16x32_bf16(xa[mt][ks], wb[ks], acc, 0, 0, 0);
                bf16x4 pk = {(bf16)(acc[0]+bv), (bf16)(acc[1]+bv),
                             (bf16)(acc[2]+bv), (bf16)(acc[3]+bv)};
                int rowd = jt * 16 + r;
                int uu = (mt * 2 + qh) ^ (rowd & 7);
                *(bf16x4*)(vT + rowd * 64 + uu * 8 + q1 * 4) = pk;
            }
        PRIO_LO();
    }

    // ---- stage 2 preloads: K A-frags, V^T A-frags (wave-local LDS) ----
    bf16x8 kf[4];
    #pragma unroll
    for (int nt = 0; nt < 4; ++nt)
        if (nt < mtc) {
            int row = nt * 16 + r;
            kf[nt] = *(const bf16x8*)(Kld + row * 32 + (qd ^ (row & 3)) * 8);
        }
    bf16x8 vf[2][2];
    #pragma unroll
    for (int dt = 0; dt < 2; ++dt)
        #pragma unroll
        for (int hk = 0; hk < 2; ++hk) {
            int row = dt * 16 + r;
            vf[dt][hk] = *(const bf16x8*)(vT + row * 64 + ((hk * 4 + qd) ^ (row & 7)) * 8);
        }
    bf16x8 wof[2][4]; float4 bo4[2];
    #pragma unroll
    for (int t2 = 0; t2 < 2; ++t2) {
        const int jg = (h * 2 + t2) * 16;
        const bf16* pw = w_out_b + (size_t)(jg + r) * 128 + qd * 8;
        #pragma unroll
        for (int s = 0; s < 4; ++s)
            wof[t2][s] = *(const bf16x8*)(pw + s * 32);
        bo4[t2] = *(const float4*)(b_out + jg + qd * 4);
    }

    const float k1 = 0.25503484f;      // (1/sqrt(32)) * log2(e)

    // ---- stage 2: per query-tile mt: S^T -> softmax -> P^T -> PV ----
    #pragma unroll
    for (int mt = 0; mt < 4; ++mt)
        if (mt < mtc) {
            // qf = B-frag Q[agent=r][d=qd*8+jj] from qreg via quad-transform
            i32x2 qa = __builtin_bit_cast(i32x2, qreg[mt][0]);
            i32x2 qb = __builtin_bit_cast(i32x2, qreg[mt][1]);
            i32x4 qw = qtrans(qa[0], qa[1], qb[0], qb[1], qodd);
            bf16x8 qf = __builtin_bit_cast(bf16x8, qw);

            f32x4 S[4];
            PRIO_HI();
            #pragma unroll
            for (int nt = 0; nt < 4; ++nt)
                if (nt < mtc) {
                    f32x4 z = {0.f,0.f,0.f,0.f};
                    S[nt] = __builtin_amdgcn_mfma_f32_16x16x32_bf16(kf[nt], qf, z, 0, 0, 0);
                }
            PRIO_LO();
            // masked softmax (log2 domain) over keys n = nt*16 + qd*4 + i
            #pragma unroll
            for (int nt = 0; nt < 4; ++nt) {
                if (nt < mtc) {
                    #pragma unroll
                    for (int i = 0; i < 4; ++i) {
                        bool kv = (nt * 16 + qd * 4 + i) < nb;
                        S[nt][i] = kv ? S[nt][i] * k1 : NEG_INF;
                    }
                } else {
                    S[nt] = (f32x4){NEG_INF, NEG_INF, NEG_INF, NEG_INF};
                }
            }
            float tm[4];
            #pragma unroll
            for (int nt = 0; nt < 4; ++nt)
                tm[nt] = fmaxf(fmaxf(S[nt][0], S[nt][1]), fmaxf(S[nt][2], S[nt][3]));
            float mx = fmaxf(fmaxf(tm[0], tm[1]), fmaxf(tm[2], tm[3]));
            mx = fmaxf(mx, __shfl_xor(mx, 16));
            mx = fmaxf(mx, __shfl_xor(mx, 32));
            float lt[4];
            #pragma unroll
            for (int nt = 0; nt < 4; ++nt) {
                float e0 = EXP2(S[nt][0] - mx), e1 = EXP2(S[nt][1] - mx);
                float e2 = EXP2(S[nt][2] - mx), e3 = EXP2(S[nt][3] - mx);
                S[nt][0] = e0; S[nt][1] = e1; S[nt][2] = e2; S[nt][3] = e3;
                lt[nt] = (e0 + e1) + (e2 + e3);
            }
            float l = (lt[0] + lt[1]) + (lt[2] + lt[3]);
            l += __shfl_xor(l, 16);
            l += __shfl_xor(l, 32);
            const float rl = 1.0f / l;
            #pragma unroll
            for (int nt = 0; nt < 4; ++nt)
                #pragma unroll
                for (int i = 0; i < 4; ++i)
                    S[nt][i] *= rl;                       // invalid keys -> exact 0

            // PV: O^T = V^T * P^T ; P^T frags via quad-transform (no bpermute)
            f32x4 o0 = {0.f,0.f,0.f,0.f}, o1 = {0.f,0.f,0.f,0.f};
            #pragma unroll
            for (int hk = 0; hk < 2; ++hk)
                if (hk * 2 < mtc) {
                    int a0 = pk2(S[2*hk  ][0], S[2*hk  ][1]);
                    int a1 = pk2(S[2*hk  ][2], S[2*hk  ][3]);
                    int b0 = pk2(S[2*hk+1][0], S[2*hk+1][1]);
                    int b1 = pk2(S[2*hk+1][2], S[2*hk+1][3]);
                    i32x4 pw4 = qtrans(a0, a1, b0, b1, qodd);
                    bf16x8 pf = __builtin_bit_cast(bf16x8, pw4);
                    PRIO_HI();
                    o0 = __builtin_amdgcn_mfma_f32_16x16x32_bf16(vf[0][hk], pf, o0, 0, 0, 0);
                    o1 = __builtin_amdgcn_mfma_f32_16x16x32_bf16(vf[1][hk], pf, o1, 0, 0, 0);
                    PRIO_LO();
                }

            // ctx^T B-frag via quad-transform -> one b128 LDS write (ctxS
            // overlays K; kf already register-resident; wave-local region)
            {
                int a0 = pk2(o0[0], o0[1]);
                int a1 = pk2(o0[2], o0[3]);
                int b0 = pk2(o1[0], o1[1]);
                int b1 = pk2(o1[2], o1[3]);
                i32x4 cw = qtrans(a0, a1, b0, b1, qodd);
                bf16x8 cf = __builtin_bit_cast(bf16x8, cw);
                *(bf16x8*)(Kld + mt * 512 + lane * 8) = cf;   // ctxS[h][mt][lane]
            }
        }
    __syncthreads();

    // ---- stage 3: out^T = W_out * ctx^T ; float4 stores ----
    #pragma unroll
    for (int mt = 0; mt < 4; ++mt)
        if (mt < mtc) {
            bf16x8 cb[4];
            #pragma unroll
            for (int s = 0; s < 4; ++s)
                cb[s] = *(const bf16x8*)(s_lds + s * 4096 + mt * 512 + lane * 8);
            const int rowa = mt * 16 + r;
            PRIO_HI();
            #pragma unroll
            for (int t2 = 0; t2 < 2; ++t2) {
                f32x4 acc = {0.f,0.f,0.f,0.f};
                #pragma unroll
                for (int s = 0; s < 4; ++s)
                    acc = __builtin_amdgcn_mfma_f32_16x16x32_bf16(wof[t2][s], cb[s], acc, 0, 0, 0);
                if (rowa < nb) {
                    float4 o4 = make_float4(acc[0] + bo4[t2].x, acc[1] + bo4[t2].y,
                                            acc[2] + bo4[t2].z, acc[3] + bo4[t2].w);
                    *(float4*)(out + ((size_t)b * 64 + rowa) * 128
                               + (w * 2 + t2) * 16 + qd * 4) = o4;
                }
            }
            PRIO_LO();
        }
}

extern "C" void kernel_launch(void* const* d_in, const int* in_sizes, int n_in,
                              void* d_out, int out_size, void* d_ws, size_t ws_size,
                              hipStream_t stream)
{
    const float* att_in = (const float*)d_in[0];
    const float* w_in   = (const float*)d_in[1];
    const float* b_in   = (const float*)d_in[2];
    const float* w_out  = (const float*)d_in[3];
    const float* b_out  = (const float*)d_in[4];
    const int*   agents = (const int*)d_in[5];

    bf16* w_in_b  = (bf16*)d_ws;                         // 49152 * 2B
    bf16* w_out_b = w_in_b + 49152;                      // 16384 * 2B
    int*  offs    = (int*)((char*)d_ws + 98304 + 32768); // 2048 * 4B @ 131072
    int*  perm    = (ws_size >= 131072 + 8192 + 8192)    // 2048 * 4B @ 139264
                    ? (int*)((char*)d_ws + 139264) : nullptr;

    prep_kernel<<<65, 256, 0, stream>>>(w_in, w_out, agents, w_in_b, w_out_b,
                                        offs, perm);
    attn_kernel<<<N_SCENES, 256, 0, stream>>>(att_in, b_in, b_out, w_in_b, w_out_b,
                                              agents, offs, perm, (float*)d_out);
}

// Round 15
// 164.632 us; speedup vs baseline: 1.0439x; 1.0188x over previous
//
#include <hip/hip_runtime.h>
#include <hip/hip_bf16.h>

typedef __bf16 bf16;
typedef __bf16 bf16x2 __attribute__((ext_vector_type(2)));
typedef __bf16 bf16x4 __attribute__((ext_vector_type(4)));
typedef __bf16 bf16x8 __attribute__((ext_vector_type(8)));
typedef float  f32x4  __attribute__((ext_vector_type(4)));
typedef int    i32x2  __attribute__((ext_vector_type(2)));
typedef int    i32x4  __attribute__((ext_vector_type(4)));

#define NEG_INF (-1e9f)
#define N_SCENES 2048

#if defined(__has_builtin)
#if __has_builtin(__builtin_amdgcn_exp2f)
#define EXP2(x) __builtin_amdgcn_exp2f(x)
#endif
#endif
#ifndef EXP2
#define EXP2(x) exp2f(x)
#endif

#define PRIO_HI() __builtin_amdgcn_s_setprio(1)
#define PRIO_LO() __builtin_amdgcn_s_setprio(0)

// v_permlane32_swap_b32: a' = {a.lo32lanes, b.lo32lanes}, b' = {a.hi, b.hi}
static __device__ __forceinline__ void pl32(int& a, int& b) {
#if defined(__has_builtin) && __has_builtin(__builtin_amdgcn_permlane32_swap)
    i32x2 res = __builtin_amdgcn_permlane32_swap(a, b, false, false);
    a = res[0]; b = res[1];
#else
    asm("v_permlane32_swap_b32 %0, %1" : "+v"(a), "+v"(b));
#endif
}

// pack two f32 -> one dword of 2 bf16 (compiler emits v_cvt_pk_bf16_f32)
static __device__ __forceinline__ int pk2(float x, float y) {
    bf16x2 t = {(bf16)x, (bf16)y};
    return __builtin_bit_cast(int, t);
}

// Quad-transpose transform (replaces the 16-bpermute quad-shuffle):
// sources a0,a1 (tile A words), b0,b1 (tile B words), each word = 2 bf16.
// Source layout: lane(r,qd') word w of tile T = elems [T*16 + qd'*4 + 2w, +1].
// Target: word j at lane(r,qd) = elems [qd*8 + 2j, +1] (A for qd<2, B else).
static __device__ __forceinline__ i32x4 qtrans(int a0, int a1, int b0, int b1,
                                               bool qodd) {
    i32x4 out;
    pl32(a0, b0);                       // a0={A.lo,B.lo}  b0={A.hi,B.hi}
    int y2 = __shfl_xor(b0, 16);
    int x2 = __shfl_xor(a0, 16);
    out[0] = qodd ? y2 : a0;
    out[2] = qodd ? b0 : x2;
    pl32(a1, b1);
    int y2b = __shfl_xor(b1, 16);
    int x2b = __shfl_xor(a1, 16);
    out[1] = qodd ? y2b : a1;
    out[3] = qodd ? b1 : x2b;
    return out;
}

// ---------------------------------------------------------------------------
// Prep: block 0: exclusive prefix sum of agents (B=2048) + LPT permutation
// (counting sort by descending nb -> heavy scenes dispatch first);
// blocks 1..64: fp32 -> bf16 weight conversion into workspace.
// ---------------------------------------------------------------------------
__global__ __launch_bounds__(256) void prep_kernel(
    const float* __restrict__ w_in, const float* __restrict__ w_out,
    const int* __restrict__ agents,
    bf16* __restrict__ w_in_b, bf16* __restrict__ w_out_b,
    int* __restrict__ offs, int* __restrict__ perm)
{
    __shared__ int tot[256];
    __shared__ int hist[64];
    __shared__ int base[64];
    const int t = threadIdx.x;
    if (blockIdx.x == 0) {
        int loc[8]; int s = 0;
        #pragma unroll
        for (int j = 0; j < 8; ++j) { loc[j] = agents[t * 8 + j]; s += loc[j]; }
        tot[t] = s;
        if (t < 64) hist[t] = 0;
        __syncthreads();
        for (int o = 1; o < 256; o <<= 1) {
            int v = (t >= o) ? tot[t - o] : 0;
            __syncthreads();
            tot[t] += v;
            __syncthreads();
        }
        int run = tot[t] - s;
        #pragma unroll
        for (int j = 0; j < 8; ++j) { offs[t * 8 + j] = run; run += loc[j]; }

        if (perm) {
            // counting sort, key k = 64 - nb (0..63): descending nb order
            #pragma unroll
            for (int j = 0; j < 8; ++j)
                atomicAdd(&hist[64 - loc[j]], 1);
            __syncthreads();
            if (t < 64) base[t] = hist[t];
            __syncthreads();
            for (int o = 1; o < 64; o <<= 1) {
                int v = (t >= o && t < 64) ? base[t - o] : 0;
                __syncthreads();
                if (t < 64) base[t] += v;
                __syncthreads();
            }
            if (t < 64) hist[t] = base[t] - hist[t];   // exclusive bucket start
            __syncthreads();
            #pragma unroll
            for (int j = 0; j < 8; ++j) {
                int rank = atomicAdd(&hist[64 - loc[j]], 1);
                perm[rank] = t * 8 + j;
            }
        }
    } else {
        int i = (blockIdx.x - 1) * 1024 + t * 4;
        float4 v; bf16* dst;
        if (i < 49152) { v = *(const float4*)(w_in + i);            dst = w_in_b + i; }
        else           { v = *(const float4*)(w_out + (i - 49152)); dst = w_out_b + (i - 49152); }
        bf16x4 o = { (bf16)v.x, (bf16)v.y, (bf16)v.z, (bf16)v.w };
        *(bf16x4*)dst = o;
    }
}

// ---------------------------------------------------------------------------
// R19: R18 (clean R7 body + setprio + LPT dispatch; attn 69.0us, total
// 167.7us -- session best, occupancy 29->37.5% from LPT) + ONE delta:
// the zero-fill of output rows [nb,64) moves from the kernel FRONT to
// AFTER stage 3. Mechanism: vmcnt counts stores as well as loads, so the
// compiler's waitcnt before stage-1's first MFMA conservatively drained
// the zero-fill stores (~500+cy HBM store latency) along with the xa
// loads -- pure added front latency, since nothing in-kernel consumes
// those stores. At the tail they are fire-and-forget (rows [nb,64) are
// disjoint from stage-3's [0,nb) -- race-free reorder). No new live
// state (loop uses nb, b, out -- all still live). Spill detector: FETCH
// > 20MB or WRITE > 70MB means allocator demotion, revert to R18.
// Structure: 4 waves, wave=head, Q in regs, K/V via 32KB LDS (swizzled),
// qtrans quad-transposes for qf/P^T/ctx^T, ctxS overlays Kld, log2-domain
// softmax, setprio(1) around MFMA clusters, LPT scene permutation.
// MFMA 16x16x32_bf16: A[m=lane&15][k=quad*8+jj], B[k=quad*8+jj][n=lane&15],
// C/D: col=lane&15, row=quad*4+reg.
// ---------------------------------------------------------------------------
__global__ __launch_bounds__(256, 4) void attn_kernel(
    const float* __restrict__ att_in,
    const float* __restrict__ b_in, const float* __restrict__ b_out,
    const bf16* __restrict__ w_in_b, const bf16* __restrict__ w_out_b,
    const int* __restrict__ agents, const int* __restrict__ offs,
    const int* __restrict__ perm,
    float* __restrict__ out)
{
    __shared__ bf16 s_lds[4 * 4096];   // 32 KB

    const int b    = perm ? perm[blockIdx.x] : blockIdx.x;
    const int tid  = threadIdx.x;
    const int lane = tid & 63;
    const int w    = tid >> 6;         // wave id == head id
    const int h    = w;
    const int r    = lane & 15;
    const int qd   = lane >> 4;        // quad 0..3
    const int q1   = qd & 1;
    const int qh   = qd >> 1;
    const bool qodd = (q1 != 0);
    const int nb   = agents[b];
    const int off  = offs[b];
    const int mtc  = (nb + 15) >> 4;   // live m-tiles (1..4)

    bf16* Kld = s_lds + h * 4096;      // K[64][32] swizzled; later ctxS[4mt][64][8]
    bf16* vT  = Kld + 2048;            // vT[32][64]

    // ---- zero vT units for agents >= mtc*16 (keep PV inputs finite) ----
    {
        bf16x4 z4 = {(bf16)0.f,(bf16)0.f,(bf16)0.f,(bf16)0.f};
        int zrow = lane >> 1, zh = lane & 1;     // 32 rows x 2 halves
        #pragma unroll
        for (int un = 2; un < 8; ++un)
            if (un >= 2 * mtc) {
                int uu = un ^ (zrow & 7);
                *(bf16x4*)(vT + zrow * 64 + uu * 8 + zh * 4) = z4;
            }
    }

    // ---- x fragments from global (rows >= nb -> 0); serve as A and B ----
    bf16x8 xa[4][4];
    #pragma unroll
    for (int mt = 0; mt < 4; ++mt) {
        const int xrow = mt * 16 + r;
        const bool vr = xrow < nb;
        const float* px = att_in + (((size_t)(off + xrow)) << 7) + qd * 8;
        #pragma unroll
        for (int ks = 0; ks < 4; ++ks) {
            float4 lo = make_float4(0.f,0.f,0.f,0.f), hi = lo;
            if (vr) {
                lo = *(const float4*)(px + ks * 32);
                hi = *(const float4*)(px + ks * 32 + 4);
            }
            xa[mt][ks] = (bf16x8){(bf16)lo.x,(bf16)lo.y,(bf16)lo.z,(bf16)lo.w,
                                  (bf16)hi.x,(bf16)hi.y,(bf16)hi.z,(bf16)hi.w};
        }
    }

    // ---- stage 1a: Q tiles -> registers (packed with bias) ----
    // qreg[mt][jt] at lane(r,qd) = Q[agent=mt*16+r][d = jt*16+qd*4+reg]+bias
    bf16x4 qreg[4][2];
    #pragma unroll
    for (int jt = 0; jt < 2; ++jt) {
        const int j0 = h * 32 + jt * 16;
        const bf16* pw = w_in_b + (size_t)(j0 + r) * 128 + qd * 8;
        bf16x8 wb[4];
        #pragma unroll
        for (int ks = 0; ks < 4; ++ks)
            wb[ks] = *(const bf16x8*)(pw + ks * 32);
        const float4 b4 = *(const float4*)(b_in + j0 + qd * 4);
        PRIO_HI();
        #pragma unroll
        for (int mt = 0; mt < 4; ++mt)
            if (mt < mtc) {
                f32x4 acc = {0.f,0.f,0.f,0.f};
                #pragma unroll
                for (int ks = 0; ks < 4; ++ks)
                    acc = __builtin_amdgcn_mfma_f32_16x16x32_bf16(wb[ks], xa[mt][ks], acc, 0, 0, 0);
                qreg[mt][jt] = (bf16x4){(bf16)(acc[0]+b4.x), (bf16)(acc[1]+b4.y),
                                        (bf16)(acc[2]+b4.z), (bf16)(acc[3]+b4.w)};
            }
        PRIO_LO();
    }

    // ---- stage 1b: K tiles -> LDS (swizzled, as R4) ----
    #pragma unroll
    for (int jt = 0; jt < 2; ++jt) {
        const int j0 = 128 + h * 32 + jt * 16;
        const bf16* pw = w_in_b + (size_t)(j0 + r) * 128 + qd * 8;
        bf16x8 wb[4];
        #pragma unroll
        for (int ks = 0; ks < 4; ++ks)
            wb[ks] = *(const bf16x8*)(pw + ks * 32);
        const float4 b4 = *(const float4*)(b_in + j0 + qd * 4);
        PRIO_HI();
        #pragma unroll
        for (int mt = 0; mt < 4; ++mt)
            if (mt < mtc) {
                f32x4 acc = {0.f,0.f,0.f,0.f};
                #pragma unroll
                for (int ks = 0; ks < 4; ++ks)
                    acc = __builtin_amdgcn_mfma_f32_16x16x32_bf16(wb[ks], xa[mt][ks], acc, 0, 0, 0);
                bf16x4 pk = {(bf16)(acc[0]+b4.x), (bf16)(acc[1]+b4.y),
                             (bf16)(acc[2]+b4.z), (bf16)(acc[3]+b4.w)};
                int rowa = mt * 16 + r;
                int uu = (jt * 2 + qh) ^ (rowa & 3);
                *(bf16x4*)(Kld + rowa * 32 + uu * 8 + q1 * 4) = pk;
            }
        PRIO_LO();
    }

    // ---- stage 1c: V tiles -> LDS transposed (as R4) ----
    #pragma unroll
    for (int jt = 0; jt < 2; ++jt) {
        const int j0 = 256 + h * 32 + jt * 16;
        const bf16* pw = w_in_b + (size_t)(j0 + r) * 128 + qd * 8;
        bf16x8 wb[4];
        #pragma unroll
        for (int ks = 0; ks < 4; ++ks)
            wb[ks] = *(const bf16x8*)(pw + ks * 32);
        const float bv = b_in[j0 + r];
        PRIO_HI();
        #pragma unroll
        for (int mt = 0; mt < 4; ++mt)
            if (mt < mtc) {
                f32x4 acc = {0.f,0.f,0.f,0.f};
                #pragma unroll
                for (int ks = 0; ks < 4; ++ks)
                    acc = __builtin_amdgcn_mfma_f32_16x16x32_bf16(xa[mt][ks], wb[ks], acc, 0, 0, 0);
                bf16x4 pk = {(bf16)(acc[0]+bv), (bf16)(acc[1]+bv),
                             (bf16)(acc[2]+bv), (bf16)(acc[3]+bv)};
                int rowd = jt * 16 + r;
                int uu = (mt * 2 + qh) ^ (rowd & 7);
                *(bf16x4*)(vT + rowd * 64 + uu * 8 + q1 * 4) = pk;
            }
        PRIO_LO();
    }

    // ---- stage 2 preloads: K A-frags, V^T A-frags (wave-local LDS) ----
    bf16x8 kf[4];
    #pragma unroll
    for (int nt = 0; nt < 4; ++nt)
        if (nt < mtc) {
            int row = nt * 16 + r;
            kf[nt] = *(const bf16x8*)(Kld + row * 32 + (qd ^ (row & 3)) * 8);
        }
    bf16x8 vf[2][2];
    #pragma unroll
    for (int dt = 0; dt < 2; ++dt)
        #pragma unroll
        for (int hk = 0; hk < 2; ++hk) {
            int row = dt * 16 + r;
            vf[dt][hk] = *(const bf16x8*)(vT + row * 64 + ((hk * 4 + qd) ^ (row & 7)) * 8);
        }
    bf16x8 wof[2][4]; float4 bo4[2];
    #pragma unroll
    for (int t2 = 0; t2 < 2; ++t2) {
        const int jg = (h * 2 + t2) * 16;
        const bf16* pw = w_out_b + (size_t)(jg + r) * 128 + qd * 8;
        #pragma unroll
        for (int s = 0; s < 4; ++s)
            wof[t2][s] = *(const bf16x8*)(pw + s * 32);
        bo4[t2] = *(const float4*)(b_out + jg + qd * 4);
    }

    const float k1 = 0.25503484f;      // (1/sqrt(32)) * log2(e)

    // ---- stage 2: per query-tile mt: S^T -> softmax -> P^T -> PV ----
    #pragma unroll
    for (int mt = 0; mt < 4; ++mt)
        if (mt < mtc) {
            // qf = B-frag Q[agent=r][d=qd*8+jj] from qreg via quad-transform
            i32x2 qa = __builtin_bit_cast(i32x2, qreg[mt][0]);
            i32x2 qb = __builtin_bit_cast(i32x2, qreg[mt][1]);
            i32x4 qw = qtrans(qa[0], qa[1], qb[0], qb[1], qodd);
            bf16x8 qf = __builtin_bit_cast(bf16x8, qw);

            f32x4 S[4];
            PRIO_HI();
            #pragma unroll
            for (int nt = 0; nt < 4; ++nt)
                if (nt < mtc) {
                    f32x4 z = {0.f,0.f,0.f,0.f};
                    S[nt] = __builtin_amdgcn_mfma_f32_16x16x32_bf16(kf[nt], qf, z, 0, 0, 0);
                }
            PRIO_LO();
            // masked softmax (log2 domain) over keys n = nt*16 + qd*4 + i
            #pragma unroll
            for (int nt = 0; nt < 4; ++nt) {
                if (nt < mtc) {
                    #pragma unroll
                    for (int i = 0; i < 4; ++i) {
                        bool kv = (nt * 16 + qd * 4 + i) < nb;
                        S[nt][i] = kv ? S[nt][i] * k1 : NEG_INF;
                    }
                } else {
                    S[nt] = (f32x4){NEG_INF, NEG_INF, NEG_INF, NEG_INF};
                }
            }
            float tm[4];
            #pragma unroll
            for (int nt = 0; nt < 4; ++nt)
                tm[nt] = fmaxf(fmaxf(S[nt][0], S[nt][1]), fmaxf(S[nt][2], S[nt][3]));
            float mx = fmaxf(fmaxf(tm[0], tm[1]), fmaxf(tm[2], tm[3]));
            mx = fmaxf(mx, __shfl_xor(mx, 16));
            mx = fmaxf(mx, __shfl_xor(mx, 32));
            float lt[4];
            #pragma unroll
            for (int nt = 0; nt < 4; ++nt) {
                float e0 = EXP2(S[nt][0] - mx), e1 = EXP2(S[nt][1] - mx);
                float e2 = EXP2(S[nt][2] - mx), e3 = EXP2(S[nt][3] - mx);
                S[nt][0] = e0; S[nt][1] = e1; S[nt][2] = e2; S[nt][3] = e3;
                lt[nt] = (e0 + e1) + (e2 + e3);
            }
            float l = (lt[0] + lt[1]) + (lt[2] + lt[3]);
            l += __shfl_xor(l, 16);
            l += __shfl_xor(l, 32);
            const float rl = 1.0f / l;
            #pragma unroll
            for (int nt = 0; nt < 4; ++nt)
                #pragma unroll
                for (int i = 0; i < 4; ++i)
                    S[nt][i] *= rl;                       // invalid keys -> exact 0

            // PV: O^T = V^T * P^T ; P^T frags via quad-transform (no bpermute)
            f32x4 o0 = {0.f,0.f,0.f,0.f}, o1 = {0.f,0.f,0.f,0.f};
            #pragma unroll
            for (int hk = 0; hk < 2; ++hk)
                if (hk * 2 < mtc) {
                    int a0 = pk2(S[2*hk  ][0], S[2*hk  ][1]);
                    int a1 = pk2(S[2*hk  ][2], S[2*hk  ][3]);
                    int b0 = pk2(S[2*hk+1][0], S[2*hk+1][1]);
                    int b1 = pk2(S[2*hk+1][2], S[2*hk+1][3]);
                    i32x4 pw4 = qtrans(a0, a1, b0, b1, qodd);
                    bf16x8 pf = __builtin_bit_cast(bf16x8, pw4);
                    PRIO_HI();
                    o0 = __builtin_amdgcn_mfma_f32_16x16x32_bf16(vf[0][hk], pf, o0, 0, 0, 0);
                    o1 = __builtin_amdgcn_mfma_f32_16x16x32_bf16(vf[1][hk], pf, o1, 0, 0, 0);
                    PRIO_LO();
                }

            // ctx^T B-frag via quad-transform -> one b128 LDS write (ctxS
            // overlays K; kf already register-resident; wave-local region)
            {
                int a0 = pk2(o0[0], o0[1]);
                int a1 = pk2(o0[2], o0[3]);
                int b0 = pk2(o1[0], o1[1]);
                int b1 = pk2(o1[2], o1[3]);
                i32x4 cw = qtrans(a0, a1, b0, b1, qodd);
                bf16x8 cf = __builtin_bit_cast(bf16x8, cw);
                *(bf16x8*)(Kld + mt * 512 + lane * 8) = cf;   // ctxS[h][mt][lane]
            }
        }
    __syncthreads();

    // ---- stage 3: out^T = W_out * ctx^T ; float4 stores ----
    #pragma unroll
    for (int mt = 0; mt < 4; ++mt)
        if (mt < mtc) {
            bf16x8 cb[4];
            #pragma unroll
            for (int s = 0; s < 4; ++s)
                cb[s] = *(const bf16x8*)(s_lds + s * 4096 + mt * 512 + lane * 8);
            const int rowa = mt * 16 + r;
            PRIO_HI();
            #pragma unroll
            for (int t2 = 0; t2 < 2; ++t2) {
                f32x4 acc = {0.f,0.f,0.f,0.f};
                #pragma unroll
                for (int s = 0; s < 4; ++s)
                    acc = __builtin_amdgcn_mfma_f32_16x16x32_bf16(wof[t2][s], cb[s], acc, 0, 0, 0);
                if (rowa < nb) {
                    float4 o4 = make_float4(acc[0] + bo4[t2].x, acc[1] + bo4[t2].y,
                                            acc[2] + bo4[t2].z, acc[3] + bo4[t2].w);
                    *(float4*)(out + ((size_t)b * 64 + rowa) * 128
                               + (w * 2 + t2) * 16 + qd * 4) = o4;
                }
            }
            PRIO_LO();
        }

    // ---- zero-fill output rows [nb, 64) -- tail, fire-and-forget ----
    // (disjoint from stage-3's [0,nb) rows; moved off the kernel front so
    // the stage-1 waitcnt no longer drains these stores)
    {
        const float4 z4 = make_float4(0.f, 0.f, 0.f, 0.f);
        const int nz = (64 - nb) * 32;
        for (int i = tid; i < nz; i += 256) {
            int row = nb + (i >> 5);
            *(float4*)(out + ((size_t)b * 64 + row) * 128 + (i & 31) * 4) = z4;
        }
    }
}

extern "C" void kernel_launch(void* const* d_in, const int* in_sizes, int n_in,
                              void* d_out, int out_size, void* d_ws, size_t ws_size,
                              hipStream_t stream)
{
    const float* att_in = (const float*)d_in[0];
    const float* w_in   = (const float*)d_in[1];
    const float* b_in   = (const float*)d_in[2];
    const float* w_out  = (const float*)d_in[3];
    const float* b_out  = (const float*)d_in[4];
    const int*   agents = (const int*)d_in[5];

    bf16* w_in_b  = (bf16*)d_ws;                         // 49152 * 2B
    bf16* w_out_b = w_in_b + 49152;                      // 16384 * 2B
    int*  offs    = (int*)((char*)d_ws + 98304 + 32768); // 2048 * 4B @ 131072
    int*  perm    = (ws_size >= 131072 + 8192 + 8192)    // 2048 * 4B @ 139264
                    ? (int*)((char*)d_ws + 139264) : nullptr;

    prep_kernel<<<65, 256, 0, stream>>>(w_in, w_out, agents, w_in_b, w_out_b,
                                        offs, perm);
    attn_kernel<<<N_SCENES, 256, 0, stream>>>(att_in, b_in, b_out, w_in_b, w_out_b,
                                              agents, offs, perm, (float*)d_out);
}

// Round 16
// 163.961 us; speedup vs baseline: 1.0482x; 1.0041x over previous
//
#include <hip/hip_runtime.h>
#include <hip/hip_bf16.h>

typedef __bf16 bf16;
typedef __bf16 bf16x2 __attribute__((ext_vector_type(2)));
typedef __bf16 bf16x4 __attribute__((ext_vector_type(4)));
typedef __bf16 bf16x8 __attribute__((ext_vector_type(8)));
typedef float  f32x4  __attribute__((ext_vector_type(4)));
typedef int    i32x2  __attribute__((ext_vector_type(2)));
typedef int    i32x4  __attribute__((ext_vector_type(4)));

#define NEG_INF (-1e9f)
#define N_SCENES 2048

#if defined(__has_builtin)
#if __has_builtin(__builtin_amdgcn_exp2f)
#define EXP2(x) __builtin_amdgcn_exp2f(x)
#endif
#endif
#ifndef EXP2
#define EXP2(x) exp2f(x)
#endif

#define PRIO_HI() __builtin_amdgcn_s_setprio(1)
#define PRIO_LO() __builtin_amdgcn_s_setprio(0)

// v_permlane32_swap_b32: a' = {a.lo32lanes, b.lo32lanes}, b' = {a.hi, b.hi}
static __device__ __forceinline__ void pl32(int& a, int& b) {
#if defined(__has_builtin) && __has_builtin(__builtin_amdgcn_permlane32_swap)
    i32x2 res = __builtin_amdgcn_permlane32_swap(a, b, false, false);
    a = res[0]; b = res[1];
#else
    asm("v_permlane32_swap_b32 %0, %1" : "+v"(a), "+v"(b));
#endif
}

// pack two f32 -> one dword of 2 bf16 (compiler emits v_cvt_pk_bf16_f32)
static __device__ __forceinline__ int pk2(float x, float y) {
    bf16x2 t = {(bf16)x, (bf16)y};
    return __builtin_bit_cast(int, t);
}

// Quad-transpose transform (replaces the 16-bpermute quad-shuffle):
// sources a0,a1 (tile A words), b0,b1 (tile B words), each word = 2 bf16.
// Source layout: lane(r,qd') word w of tile T = elems [T*16 + qd'*4 + 2w, +1].
// Target: word j at lane(r,qd) = elems [qd*8 + 2j, +1] (A for qd<2, B else).
static __device__ __forceinline__ i32x4 qtrans(int a0, int a1, int b0, int b1,
                                               bool qodd) {
    i32x4 out;
    pl32(a0, b0);                       // a0={A.lo,B.lo}  b0={A.hi,B.hi}
    int y2 = __shfl_xor(b0, 16);
    int x2 = __shfl_xor(a0, 16);
    out[0] = qodd ? y2 : a0;
    out[2] = qodd ? b0 : x2;
    pl32(a1, b1);
    int y2b = __shfl_xor(b1, 16);
    int x2b = __shfl_xor(a1, 16);
    out[1] = qodd ? y2b : a1;
    out[3] = qodd ? b1 : x2b;
    return out;
}

// ---------------------------------------------------------------------------
// Prep: block 0: exclusive prefix sum of agents (B=2048) + LPT schedule
// (counting sort by descending nb); emits packed per-slot descriptor
// desc[slot] = { b | nb<<16, off } so attn's front chain is ONE uniform
// s_load instead of perm -> agents/offs (2-deep L2 chain). Falls back to
// perm-only if workspace is small. Blocks 1..64: fp32 -> bf16 weights.
// ---------------------------------------------------------------------------
__global__ __launch_bounds__(256) void prep_kernel(
    const float* __restrict__ w_in, const float* __restrict__ w_out,
    const int* __restrict__ agents,
    bf16* __restrict__ w_in_b, bf16* __restrict__ w_out_b,
    int* __restrict__ offs, int* __restrict__ perm, int2* __restrict__ desc)
{
    __shared__ int tot[256];
    __shared__ int hist[64];
    __shared__ int base[64];
    const int t = threadIdx.x;
    if (blockIdx.x == 0) {
        int loc[8]; int off_loc[8]; int s = 0;
        #pragma unroll
        for (int j = 0; j < 8; ++j) { loc[j] = agents[t * 8 + j]; s += loc[j]; }
        tot[t] = s;
        if (t < 64) hist[t] = 0;
        __syncthreads();
        for (int o = 1; o < 256; o <<= 1) {
            int v = (t >= o) ? tot[t - o] : 0;
            __syncthreads();
            tot[t] += v;
            __syncthreads();
        }
        int run = tot[t] - s;
        #pragma unroll
        for (int j = 0; j < 8; ++j) {
            offs[t * 8 + j] = run; off_loc[j] = run; run += loc[j];
        }

        if (desc || perm) {
            // counting sort, key k = 64 - nb (0..63): descending nb order
            #pragma unroll
            for (int j = 0; j < 8; ++j)
                atomicAdd(&hist[64 - loc[j]], 1);
            __syncthreads();
            if (t < 64) base[t] = hist[t];
            __syncthreads();
            for (int o = 1; o < 64; o <<= 1) {
                int v = (t >= o && t < 64) ? base[t - o] : 0;
                __syncthreads();
                if (t < 64) base[t] += v;
                __syncthreads();
            }
            if (t < 64) hist[t] = base[t] - hist[t];   // exclusive bucket start
            __syncthreads();
            #pragma unroll
            for (int j = 0; j < 8; ++j) {
                int rank = atomicAdd(&hist[64 - loc[j]], 1);
                if (desc) desc[rank] = make_int2((t * 8 + j) | (loc[j] << 16),
                                                 off_loc[j]);
                else      perm[rank] = t * 8 + j;
            }
        }
    } else {
        int i = (blockIdx.x - 1) * 1024 + t * 4;
        float4 v; bf16* dst;
        if (i < 49152) { v = *(const float4*)(w_in + i);            dst = w_in_b + i; }
        else           { v = *(const float4*)(w_out + (i - 49152)); dst = w_out_b + (i - 49152); }
        bf16x4 o = { (bf16)v.x, (bf16)v.y, (bf16)v.z, (bf16)v.w };
        *(bf16x4*)dst = o;
    }
}

// ---------------------------------------------------------------------------
// R20: R19 (clean R7 body + setprio + LPT + tail zero-fill; attn 66.9us,
// total 164.6us -- session best) + ONE scalar-only delta: packed LPT
// descriptor. The block front was a 2-deep uniform scalar-load chain
// (perm[bid] ~300-500cy L2, THEN agents[b]/offs[b] another ~300-500cy)
// before xa address calc could start. prep now emits desc[slot] =
// {b|nb<<16, off}: one s_load_dwordx2 replaces the chain. SGPR-only IR
// change at the kernel top -- no vector-array/layout perturbation (the
// proven R14-class spill triggers). Launcher fallback ladder: desc ->
// perm (R18-verified ws size) -> identity. Spill detector: FETCH > 20MB
// or WRITE > 70MB means allocator demotion, revert to R19.
// Structure: 4 waves, wave=head, Q in regs, K/V via 32KB LDS (swizzled),
// qtrans quad-transposes for qf/P^T/ctx^T, ctxS overlays Kld, log2-domain
// softmax, setprio(1) around MFMA clusters, LPT dispatch, tail zero-fill.
// MFMA 16x16x32_bf16: A[m=lane&15][k=quad*8+jj], B[k=quad*8+jj][n=lane&15],
// C/D: col=lane&15, row=quad*4+reg.
// ---------------------------------------------------------------------------
__global__ __launch_bounds__(256, 4) void attn_kernel(
    const float* __restrict__ att_in,
    const float* __restrict__ b_in, const float* __restrict__ b_out,
    const bf16* __restrict__ w_in_b, const bf16* __restrict__ w_out_b,
    const int* __restrict__ agents, const int* __restrict__ offs,
    const int* __restrict__ perm, const int2* __restrict__ desc,
    float* __restrict__ out)
{
    __shared__ bf16 s_lds[4 * 4096];   // 32 KB

    int b, nb, off;
    if (desc) {
        int2 d = desc[blockIdx.x];
        b  = d.x & 0xffff;
        nb = ((unsigned)d.x) >> 16;
        off = d.y;
    } else {
        b  = perm ? perm[blockIdx.x] : blockIdx.x;
        nb = agents[b];
        off = offs[b];
    }
    const int tid  = threadIdx.x;
    const int lane = tid & 63;
    const int w    = tid >> 6;         // wave id == head id
    const int h    = w;
    const int r    = lane & 15;
    const int qd   = lane >> 4;        // quad 0..3
    const int q1   = qd & 1;
    const int qh   = qd >> 1;
    const bool qodd = (q1 != 0);
    const int mtc  = (nb + 15) >> 4;   // live m-tiles (1..4)

    bf16* Kld = s_lds + h * 4096;      // K[64][32] swizzled; later ctxS[4mt][64][8]
    bf16* vT  = Kld + 2048;            // vT[32][64]

    // ---- zero vT units for agents >= mtc*16 (keep PV inputs finite) ----
    {
        bf16x4 z4 = {(bf16)0.f,(bf16)0.f,(bf16)0.f,(bf16)0.f};
        int zrow = lane >> 1, zh = lane & 1;     // 32 rows x 2 halves
        #pragma unroll
        for (int un = 2; un < 8; ++un)
            if (un >= 2 * mtc) {
                int uu = un ^ (zrow & 7);
                *(bf16x4*)(vT + zrow * 64 + uu * 8 + zh * 4) = z4;
            }
    }

    // ---- x fragments from global (rows >= nb -> 0); serve as A and B ----
    bf16x8 xa[4][4];
    #pragma unroll
    for (int mt = 0; mt < 4; ++mt) {
        const int xrow = mt * 16 + r;
        const bool vr = xrow < nb;
        const float* px = att_in + (((size_t)(off + xrow)) << 7) + qd * 8;
        #pragma unroll
        for (int ks = 0; ks < 4; ++ks) {
            float4 lo = make_float4(0.f,0.f,0.f,0.f), hi = lo;
            if (vr) {
                lo = *(const float4*)(px + ks * 32);
                hi = *(const float4*)(px + ks * 32 + 4);
            }
            xa[mt][ks] = (bf16x8){(bf16)lo.x,(bf16)lo.y,(bf16)lo.z,(bf16)lo.w,
                                  (bf16)hi.x,(bf16)hi.y,(bf16)hi.z,(bf16)hi.w};
        }
    }

    // ---- stage 1a: Q tiles -> registers (packed with bias) ----
    // qreg[mt][jt] at lane(r,qd) = Q[agent=mt*16+r][d = jt*16+qd*4+reg]+bias
    bf16x4 qreg[4][2];
    #pragma unroll
    for (int jt = 0; jt < 2; ++jt) {
        const int j0 = h * 32 + jt * 16;
        const bf16* pw = w_in_b + (size_t)(j0 + r) * 128 + qd * 8;
        bf16x8 wb[4];
        #pragma unroll
        for (int ks = 0; ks < 4; ++ks)
            wb[ks] = *(const bf16x8*)(pw + ks * 32);
        const float4 b4 = *(const float4*)(b_in + j0 + qd * 4);
        PRIO_HI();
        #pragma unroll
        for (int mt = 0; mt < 4; ++mt)
            if (mt < mtc) {
                f32x4 acc = {0.f,0.f,0.f,0.f};
                #pragma unroll
                for (int ks = 0; ks < 4; ++ks)
                    acc = __builtin_amdgcn_mfma_f32_16x16x32_bf16(wb[ks], xa[mt][ks], acc, 0, 0, 0);
                qreg[mt][jt] = (bf16x4){(bf16)(acc[0]+b4.x), (bf16)(acc[1]+b4.y),
                                        (bf16)(acc[2]+b4.z), (bf16)(acc[3]+b4.w)};
            }
        PRIO_LO();
    }

    // ---- stage 1b: K tiles -> LDS (swizzled, as R4) ----
    #pragma unroll
    for (int jt = 0; jt < 2; ++jt) {
        const int j0 = 128 + h * 32 + jt * 16;
        const bf16* pw = w_in_b + (size_t)(j0 + r) * 128 + qd * 8;
        bf16x8 wb[4];
        #pragma unroll
        for (int ks = 0; ks < 4; ++ks)
            wb[ks] = *(const bf16x8*)(pw + ks * 32);
        const float4 b4 = *(const float4*)(b_in + j0 + qd * 4);
        PRIO_HI();
        #pragma unroll
        for (int mt = 0; mt < 4; ++mt)
            if (mt < mtc) {
                f32x4 acc = {0.f,0.f,0.f,0.f};
                #pragma unroll
                for (int ks = 0; ks < 4; ++ks)
                    acc = __builtin_amdgcn_mfma_f32_16x16x32_bf16(wb[ks], xa[mt][ks], acc, 0, 0, 0);
                bf16x4 pk = {(bf16)(acc[0]+b4.x), (bf16)(acc[1]+b4.y),
                             (bf16)(acc[2]+b4.z), (bf16)(acc[3]+b4.w)};
                int rowa = mt * 16 + r;
                int uu = (jt * 2 + qh) ^ (rowa & 3);
                *(bf16x4*)(Kld + rowa * 32 + uu * 8 + q1 * 4) = pk;
            }
        PRIO_LO();
    }

    // ---- stage 1c: V tiles -> LDS transposed (as R4) ----
    #pragma unroll
    for (int jt = 0; jt < 2; ++jt) {
        const int j0 = 256 + h * 32 + jt * 16;
        const bf16* pw = w_in_b + (size_t)(j0 + r) * 128 + qd * 8;
        bf16x8 wb[4];
        #pragma unroll
        for (int ks = 0; ks < 4; ++ks)
            wb[ks] = *(const bf16x8*)(pw + ks * 32);
        const float bv = b_in[j0 + r];
        PRIO_HI();
        #pragma unroll
        for (int mt = 0; mt < 4; ++mt)
            if (mt < mtc) {
                f32x4 acc = {0.f,0.f,0.f,0.f};
                #pragma unroll
                for (int ks = 0; ks < 4; ++ks)
                    acc = __builtin_amdgcn_mfma_f32_16x16x32_bf16(xa[mt][ks], wb[ks], acc, 0, 0, 0);
                bf16x4 pk = {(bf16)(acc[0]+bv), (bf16)(acc[1]+bv),
                             (bf16)(acc[2]+bv), (bf16)(acc[3]+bv)};
                int rowd = jt * 16 + r;
                int uu = (mt * 2 + qh) ^ (rowd & 7);
                *(bf16x4*)(vT + rowd * 64 + uu * 8 + q1 * 4) = pk;
            }
        PRIO_LO();
    }

    // ---- stage 2 preloads: K A-frags, V^T A-frags (wave-local LDS) ----
    bf16x8 kf[4];
    #pragma unroll
    for (int nt = 0; nt < 4; ++nt)
        if (nt < mtc) {
            int row = nt * 16 + r;
            kf[nt] = *(const bf16x8*)(Kld + row * 32 + (qd ^ (row & 3)) * 8);
        }
    bf16x8 vf[2][2];
    #pragma unroll
    for (int dt = 0; dt < 2; ++dt)
        #pragma unroll
        for (int hk = 0; hk < 2; ++hk) {
            int row = dt * 16 + r;
            vf[dt][hk] = *(const bf16x8*)(vT + row * 64 + ((hk * 4 + qd) ^ (row & 7)) * 8);
        }
    bf16x8 wof[2][4]; float4 bo4[2];
    #pragma unroll
    for (int t2 = 0; t2 < 2; ++t2) {
        const int jg = (h * 2 + t2) * 16;
        const bf16* pw = w_out_b + (size_t)(jg + r) * 128 + qd * 8;
        #pragma unroll
        for (int s = 0; s < 4; ++s)
            wof[t2][s] = *(const bf16x8*)(pw + s * 32);
        bo4[t2] = *(const float4*)(b_out + jg + qd * 4);
    }

    const float k1 = 0.25503484f;      // (1/sqrt(32)) * log2(e)

    // ---- stage 2: per query-tile mt: S^T -> softmax -> P^T -> PV ----
    #pragma unroll
    for (int mt = 0; mt < 4; ++mt)
        if (mt < mtc) {
            // qf = B-frag Q[agent=r][d=qd*8+jj] from qreg via quad-transform
            i32x2 qa = __builtin_bit_cast(i32x2, qreg[mt][0]);
            i32x2 qb = __builtin_bit_cast(i32x2, qreg[mt][1]);
            i32x4 qw = qtrans(qa[0], qa[1], qb[0], qb[1], qodd);
            bf16x8 qf = __builtin_bit_cast(bf16x8, qw);

            f32x4 S[4];
            PRIO_HI();
            #pragma unroll
            for (int nt = 0; nt < 4; ++nt)
                if (nt < mtc) {
                    f32x4 z = {0.f,0.f,0.f,0.f};
                    S[nt] = __builtin_amdgcn_mfma_f32_16x16x32_bf16(kf[nt], qf, z, 0, 0, 0);
                }
            PRIO_LO();
            // masked softmax (log2 domain) over keys n = nt*16 + qd*4 + i
            #pragma unroll
            for (int nt = 0; nt < 4; ++nt) {
                if (nt < mtc) {
                    #pragma unroll
                    for (int i = 0; i < 4; ++i) {
                        bool kv = (nt * 16 + qd * 4 + i) < nb;
                        S[nt][i] = kv ? S[nt][i] * k1 : NEG_INF;
                    }
                } else {
                    S[nt] = (f32x4){NEG_INF, NEG_INF, NEG_INF, NEG_INF};
                }
            }
            float tm[4];
            #pragma unroll
            for (int nt = 0; nt < 4; ++nt)
                tm[nt] = fmaxf(fmaxf(S[nt][0], S[nt][1]), fmaxf(S[nt][2], S[nt][3]));
            float mx = fmaxf(fmaxf(tm[0], tm[1]), fmaxf(tm[2], tm[3]));
            mx = fmaxf(mx, __shfl_xor(mx, 16));
            mx = fmaxf(mx, __shfl_xor(mx, 32));
            float lt[4];
            #pragma unroll
            for (int nt = 0; nt < 4; ++nt) {
                float e0 = EXP2(S[nt][0] - mx), e1 = EXP2(S[nt][1] - mx);
                float e2 = EXP2(S[nt][2] - mx), e3 = EXP2(S[nt][3] - mx);
                S[nt][0] = e0; S[nt][1] = e1; S[nt][2] = e2; S[nt][3] = e3;
                lt[nt] = (e0 + e1) + (e2 + e3);
            }
            float l = (lt[0] + lt[1]) + (lt[2] + lt[3]);
            l += __shfl_xor(l, 16);
            l += __shfl_xor(l, 32);
            const float rl = 1.0f / l;
            #pragma unroll
            for (int nt = 0; nt < 4; ++nt)
                #pragma unroll
                for (int i = 0; i < 4; ++i)
                    S[nt][i] *= rl;                       // invalid keys -> exact 0

            // PV: O^T = V^T * P^T ; P^T frags via quad-transform (no bpermute)
            f32x4 o0 = {0.f,0.f,0.f,0.f}, o1 = {0.f,0.f,0.f,0.f};
            #pragma unroll
            for (int hk = 0; hk < 2; ++hk)
                if (hk * 2 < mtc) {
                    int a0 = pk2(S[2*hk  ][0], S[2*hk  ][1]);
                    int a1 = pk2(S[2*hk  ][2], S[2*hk  ][3]);
                    int b0 = pk2(S[2*hk+1][0], S[2*hk+1][1]);
                    int b1 = pk2(S[2*hk+1][2], S[2*hk+1][3]);
                    i32x4 pw4 = qtrans(a0, a1, b0, b1, qodd);
                    bf16x8 pf = __builtin_bit_cast(bf16x8, pw4);
                    PRIO_HI();
                    o0 = __builtin_amdgcn_mfma_f32_16x16x32_bf16(vf[0][hk], pf, o0, 0, 0, 0);
                    o1 = __builtin_amdgcn_mfma_f32_16x16x32_bf16(vf[1][hk], pf, o1, 0, 0, 0);
                    PRIO_LO();
                }

            // ctx^T B-frag via quad-transform -> one b128 LDS write (ctxS
            // overlays K; kf already register-resident; wave-local region)
            {
                int a0 = pk2(o0[0], o0[1]);
                int a1 = pk2(o0[2], o0[3]);
                int b0 = pk2(o1[0], o1[1]);
                int b1 = pk2(o1[2], o1[3]);
                i32x4 cw = qtrans(a0, a1, b0, b1, qodd);
                bf16x8 cf = __builtin_bit_cast(bf16x8, cw);
                *(bf16x8*)(Kld + mt * 512 + lane * 8) = cf;   // ctxS[h][mt][lane]
            }
        }
    __syncthreads();

    // ---- stage 3: out^T = W_out * ctx^T ; float4 stores ----
    #pragma unroll
    for (int mt = 0; mt < 4; ++mt)
        if (mt < mtc) {
            bf16x8 cb[4];
            #pragma unroll
            for (int s = 0; s < 4; ++s)
                cb[s] = *(const bf16x8*)(s_lds + s * 4096 + mt * 512 + lane * 8);
            const int rowa = mt * 16 + r;
            PRIO_HI();
            #pragma unroll
            for (int t2 = 0; t2 < 2; ++t2) {
                f32x4 acc = {0.f,0.f,0.f,0.f};
                #pragma unroll
                for (int s = 0; s < 4; ++s)
                    acc = __builtin_amdgcn_mfma_f32_16x16x32_bf16(wof[t2][s], cb[s], acc, 0, 0, 0);
                if (rowa < nb) {
                    float4 o4 = make_float4(acc[0] + bo4[t2].x, acc[1] + bo4[t2].y,
                                            acc[2] + bo4[t2].z, acc[3] + bo4[t2].w);
                    *(float4*)(out + ((size_t)b * 64 + rowa) * 128
                               + (w * 2 + t2) * 16 + qd * 4) = o4;
                }
            }
            PRIO_LO();
        }

    // ---- zero-fill output rows [nb, 64) -- tail, fire-and-forget ----
    // (disjoint from stage-3's [0,nb) rows; off the kernel front so the
    // stage-1 waitcnt no longer drains these stores)
    {
        const float4 z4 = make_float4(0.f, 0.f, 0.f, 0.f);
        const int nz = (64 - nb) * 32;
        for (int i = tid; i < nz; i += 256) {
            int row = nb + (i >> 5);
            *(float4*)(out + ((size_t)b * 64 + row) * 128 + (i & 31) * 4) = z4;
        }
    }
}

extern "C" void kernel_launch(void* const* d_in, const int* in_sizes, int n_in,
                              void* d_out, int out_size, void* d_ws, size_t ws_size,
                              hipStream_t stream)
{
    const float* att_in = (const float*)d_in[0];
    const float* w_in   = (const float*)d_in[1];
    const float* b_in   = (const float*)d_in[2];
    const float* w_out  = (const float*)d_in[3];
    const float* b_out  = (const float*)d_in[4];
    const int*   agents = (const int*)d_in[5];

    bf16* w_in_b  = (bf16*)d_ws;                         // 49152 * 2B
    bf16* w_out_b = w_in_b + 49152;                      // 16384 * 2B
    int*  offs    = (int*)((char*)d_ws + 131072);        // 2048 * 4B @ 131072
    int*  perm    = nullptr;
    int2* desc    = nullptr;
    if (ws_size >= 139264 + 16384)                       // desc: 2048 * 8B
        desc = (int2*)((char*)d_ws + 139264);
    else if (ws_size >= 139264 + 8192)                   // perm: 2048 * 4B
        perm = (int*)((char*)d_ws + 139264);

    prep_kernel<<<65, 256, 0, stream>>>(w_in, w_out, agents, w_in_b, w_out_b,
                                        offs, perm, desc);
    attn_kernel<<<N_SCENES, 256, 0, stream>>>(att_in, b_in, b_out, w_in_b, w_out_b,
                                              agents, offs, perm, desc,
                                              (float*)d_out);
}

// Round 17
// 163.269 us; speedup vs baseline: 1.0526x; 1.0042x over previous
//
#include <hip/hip_runtime.h>
#include <hip/hip_bf16.h>

typedef __bf16 bf16;
typedef __bf16 bf16x2 __attribute__((ext_vector_type(2)));
typedef __bf16 bf16x4 __attribute__((ext_vector_type(4)));
typedef __bf16 bf16x8 __attribute__((ext_vector_type(8)));
typedef float  f32x4  __attribute__((ext_vector_type(4)));
typedef int    i32x2  __attribute__((ext_vector_type(2)));
typedef int    i32x4  __attribute__((ext_vector_type(4)));

#define NEG_INF (-1e9f)
#define N_SCENES 2048

#if defined(__has_builtin)
#if __has_builtin(__builtin_amdgcn_exp2f)
#define EXP2(x) __builtin_amdgcn_exp2f(x)
#endif
#endif
#ifndef EXP2
#define EXP2(x) exp2f(x)
#endif

#define PRIO_HI() __builtin_amdgcn_s_setprio(1)
#define PRIO_LO() __builtin_amdgcn_s_setprio(0)

// v_permlane32_swap_b32: a' = {a.lo32lanes, b.lo32lanes}, b' = {a.hi, b.hi}
static __device__ __forceinline__ void pl32(int& a, int& b) {
#if defined(__has_builtin) && __has_builtin(__builtin_amdgcn_permlane32_swap)
    i32x2 res = __builtin_amdgcn_permlane32_swap(a, b, false, false);
    a = res[0]; b = res[1];
#else
    asm("v_permlane32_swap_b32 %0, %1" : "+v"(a), "+v"(b));
#endif
}

// pack two f32 -> one dword of 2 bf16 (compiler emits v_cvt_pk_bf16_f32)
static __device__ __forceinline__ int pk2(float x, float y) {
    bf16x2 t = {(bf16)x, (bf16)y};
    return __builtin_bit_cast(int, t);
}

// Quad-transpose transform (replaces the 16-bpermute quad-shuffle):
// sources a0,a1 (tile A words), b0,b1 (tile B words), each word = 2 bf16.
// Source layout: lane(r,qd') word w of tile T = elems [T*16 + qd'*4 + 2w, +1].
// Target: word j at lane(r,qd) = elems [qd*8 + 2j, +1] (A for qd<2, B else).
static __device__ __forceinline__ i32x4 qtrans(int a0, int a1, int b0, int b1,
                                               bool qodd) {
    i32x4 out;
    pl32(a0, b0);                       // a0={A.lo,B.lo}  b0={A.hi,B.hi}
    int y2 = __shfl_xor(b0, 16);
    int x2 = __shfl_xor(a0, 16);
    out[0] = qodd ? y2 : a0;
    out[2] = qodd ? b0 : x2;
    pl32(a1, b1);
    int y2b = __shfl_xor(b1, 16);
    int x2b = __shfl_xor(a1, 16);
    out[1] = qodd ? y2b : a1;
    out[3] = qodd ? b1 : x2b;
    return out;
}

// ---------------------------------------------------------------------------
// Prep: block 0: exclusive prefix sum of agents (B=2048) + LPT schedule
// (counting sort by descending nb); emits packed per-slot descriptor
// desc[slot] = { b | nb<<16, off } so attn's front chain is ONE uniform
// s_load instead of perm -> agents/offs (2-deep L2 chain). Falls back to
// perm-only if workspace is small. Blocks 1..64: fp32 -> bf16 weights.
// ---------------------------------------------------------------------------
__global__ __launch_bounds__(256) void prep_kernel(
    const float* __restrict__ w_in, const float* __restrict__ w_out,
    const int* __restrict__ agents,
    bf16* __restrict__ w_in_b, bf16* __restrict__ w_out_b,
    int* __restrict__ offs, int* __restrict__ perm, int2* __restrict__ desc)
{
    __shared__ int tot[256];
    __shared__ int hist[64];
    __shared__ int base[64];
    const int t = threadIdx.x;
    if (blockIdx.x == 0) {
        int loc[8]; int off_loc[8]; int s = 0;
        #pragma unroll
        for (int j = 0; j < 8; ++j) { loc[j] = agents[t * 8 + j]; s += loc[j]; }
        tot[t] = s;
        if (t < 64) hist[t] = 0;
        __syncthreads();
        for (int o = 1; o < 256; o <<= 1) {
            int v = (t >= o) ? tot[t - o] : 0;
            __syncthreads();
            tot[t] += v;
            __syncthreads();
        }
        int run = tot[t] - s;
        #pragma unroll
        for (int j = 0; j < 8; ++j) {
            offs[t * 8 + j] = run; off_loc[j] = run; run += loc[j];
        }

        if (desc || perm) {
            // counting sort, key k = 64 - nb (0..63): descending nb order
            #pragma unroll
            for (int j = 0; j < 8; ++j)
                atomicAdd(&hist[64 - loc[j]], 1);
            __syncthreads();
            if (t < 64) base[t] = hist[t];
            __syncthreads();
            for (int o = 1; o < 64; o <<= 1) {
                int v = (t >= o && t < 64) ? base[t - o] : 0;
                __syncthreads();
                if (t < 64) base[t] += v;
                __syncthreads();
            }
            if (t < 64) hist[t] = base[t] - hist[t];   // exclusive bucket start
            __syncthreads();
            #pragma unroll
            for (int j = 0; j < 8; ++j) {
                int rank = atomicAdd(&hist[64 - loc[j]], 1);
                if (desc) desc[rank] = make_int2((t * 8 + j) | (loc[j] << 16),
                                                 off_loc[j]);
                else      perm[rank] = t * 8 + j;
            }
        }
    } else {
        int i = (blockIdx.x - 1) * 1024 + t * 4;
        float4 v; bf16* dst;
        if (i < 49152) { v = *(const float4*)(w_in + i);            dst = w_in_b + i; }
        else           { v = *(const float4*)(w_out + (i - 49152)); dst = w_out_b + (i - 49152); }
        bf16x4 o = { (bf16)v.x, (bf16)v.y, (bf16)v.z, (bf16)v.w };
        *(bf16x4*)dst = o;
    }
}

// ---------------------------------------------------------------------------
// R21: R20 (clean R7 body + setprio + LPT + tail zero-fill + desc; attn
// 66.5us, total 164.0 -- session best) + ONE delta, isolating half of the
// R14 spill bundle: (1/sqrt32)*log2e folded into the qreg bf16 pack,
// deleting the per-mt 16-VALU S*k1 pass from the softmax chain. This is
// a scalar-constant change to the Q pack only -- NOT the array-type
// repack (pk2-xa) which is the other R14-delta suspect. R11 carried both
// deltas clean at budget 168; R14 with both at 128 spilled; R15 with
// neither at 128 was clean. This A/B isolates the fold at 128.
// Spill detector: FETCH > 20MB or WRITE > 70MB -> fold is the trigger,
// revert to R20 as final. absmax expected ~0.0044 (passed R11/R12/R13).
// Structure: 4 waves, wave=head, Q in regs, K/V via 32KB LDS (swizzled),
// qtrans quad-transposes for qf/P^T/ctx^T, ctxS overlays Kld, log2-domain
// softmax (scale pre-folded), setprio around MFMA, LPT dispatch via desc,
// tail zero-fill.
// MFMA 16x16x32_bf16: A[m=lane&15][k=quad*8+jj], B[k=quad*8+jj][n=lane&15],
// C/D: col=lane&15, row=quad*4+reg.
// ---------------------------------------------------------------------------
__global__ __launch_bounds__(256, 4) void attn_kernel(
    const float* __restrict__ att_in,
    const float* __restrict__ b_in, const float* __restrict__ b_out,
    const bf16* __restrict__ w_in_b, const bf16* __restrict__ w_out_b,
    const int* __restrict__ agents, const int* __restrict__ offs,
    const int* __restrict__ perm, const int2* __restrict__ desc,
    float* __restrict__ out)
{
    __shared__ bf16 s_lds[4 * 4096];   // 32 KB

    int b, nb, off;
    if (desc) {
        int2 d = desc[blockIdx.x];
        b  = d.x & 0xffff;
        nb = ((unsigned)d.x) >> 16;
        off = d.y;
    } else {
        b  = perm ? perm[blockIdx.x] : blockIdx.x;
        nb = agents[b];
        off = offs[b];
    }
    const int tid  = threadIdx.x;
    const int lane = tid & 63;
    const int w    = tid >> 6;         // wave id == head id
    const int h    = w;
    const int r    = lane & 15;
    const int qd   = lane >> 4;        // quad 0..3
    const int q1   = qd & 1;
    const int qh   = qd >> 1;
    const bool qodd = (q1 != 0);
    const int mtc  = (nb + 15) >> 4;   // live m-tiles (1..4)

    bf16* Kld = s_lds + h * 4096;      // K[64][32] swizzled; later ctxS[4mt][64][8]
    bf16* vT  = Kld + 2048;            // vT[32][64]

    // ---- zero vT units for agents >= mtc*16 (keep PV inputs finite) ----
    {
        bf16x4 z4 = {(bf16)0.f,(bf16)0.f,(bf16)0.f,(bf16)0.f};
        int zrow = lane >> 1, zh = lane & 1;     // 32 rows x 2 halves
        #pragma unroll
        for (int un = 2; un < 8; ++un)
            if (un >= 2 * mtc) {
                int uu = un ^ (zrow & 7);
                *(bf16x4*)(vT + zrow * 64 + uu * 8 + zh * 4) = z4;
            }
    }

    // ---- x fragments from global (rows >= nb -> 0); serve as A and B ----
    bf16x8 xa[4][4];
    #pragma unroll
    for (int mt = 0; mt < 4; ++mt) {
        const int xrow = mt * 16 + r;
        const bool vr = xrow < nb;
        const float* px = att_in + (((size_t)(off + xrow)) << 7) + qd * 8;
        #pragma unroll
        for (int ks = 0; ks < 4; ++ks) {
            float4 lo = make_float4(0.f,0.f,0.f,0.f), hi = lo;
            if (vr) {
                lo = *(const float4*)(px + ks * 32);
                hi = *(const float4*)(px + ks * 32 + 4);
            }
            xa[mt][ks] = (bf16x8){(bf16)lo.x,(bf16)lo.y,(bf16)lo.z,(bf16)lo.w,
                                  (bf16)hi.x,(bf16)hi.y,(bf16)hi.z,(bf16)hi.w};
        }
    }

    const float SC = 0.25503484f;      // (1/sqrt(32)) * log2(e), folded into Q

    // ---- stage 1a: Q tiles -> registers (packed, bias+scale folded) ----
    // qreg[mt][jt] at lane(r,qd) = SC*(Q[agent=mt*16+r][jt*16+qd*4+reg]+bias)
    bf16x4 qreg[4][2];
    #pragma unroll
    for (int jt = 0; jt < 2; ++jt) {
        const int j0 = h * 32 + jt * 16;
        const bf16* pw = w_in_b + (size_t)(j0 + r) * 128 + qd * 8;
        bf16x8 wb[4];
        #pragma unroll
        for (int ks = 0; ks < 4; ++ks)
            wb[ks] = *(const bf16x8*)(pw + ks * 32);
        const float4 b4 = *(const float4*)(b_in + j0 + qd * 4);
        PRIO_HI();
        #pragma unroll
        for (int mt = 0; mt < 4; ++mt)
            if (mt < mtc) {
                f32x4 acc = {0.f,0.f,0.f,0.f};
                #pragma unroll
                for (int ks = 0; ks < 4; ++ks)
                    acc = __builtin_amdgcn_mfma_f32_16x16x32_bf16(wb[ks], xa[mt][ks], acc, 0, 0, 0);
                qreg[mt][jt] = (bf16x4){(bf16)((acc[0]+b4.x)*SC), (bf16)((acc[1]+b4.y)*SC),
                                        (bf16)((acc[2]+b4.z)*SC), (bf16)((acc[3]+b4.w)*SC)};
            }
        PRIO_LO();
    }

    // ---- stage 1b: K tiles -> LDS (swizzled, as R4) ----
    #pragma unroll
    for (int jt = 0; jt < 2; ++jt) {
        const int j0 = 128 + h * 32 + jt * 16;
        const bf16* pw = w_in_b + (size_t)(j0 + r) * 128 + qd * 8;
        bf16x8 wb[4];
        #pragma unroll
        for (int ks = 0; ks < 4; ++ks)
            wb[ks] = *(const bf16x8*)(pw + ks * 32);
        const float4 b4 = *(const float4*)(b_in + j0 + qd * 4);
        PRIO_HI();
        #pragma unroll
        for (int mt = 0; mt < 4; ++mt)
            if (mt < mtc) {
                f32x4 acc = {0.f,0.f,0.f,0.f};
                #pragma unroll
                for (int ks = 0; ks < 4; ++ks)
                    acc = __builtin_amdgcn_mfma_f32_16x16x32_bf16(wb[ks], xa[mt][ks], acc, 0, 0, 0);
                bf16x4 pk = {(bf16)(acc[0]+b4.x), (bf16)(acc[1]+b4.y),
                             (bf16)(acc[2]+b4.z), (bf16)(acc[3]+b4.w)};
                int rowa = mt * 16 + r;
                int uu = (jt * 2 + qh) ^ (rowa & 3);
                *(bf16x4*)(Kld + rowa * 32 + uu * 8 + q1 * 4) = pk;
            }
        PRIO_LO();
    }

    // ---- stage 1c: V tiles -> LDS transposed (as R4) ----
    #pragma unroll
    for (int jt = 0; jt < 2; ++jt) {
        const int j0 = 256 + h * 32 + jt * 16;
        const bf16* pw = w_in_b + (size_t)(j0 + r) * 128 + qd * 8;
        bf16x8 wb[4];
        #pragma unroll
        for (int ks = 0; ks < 4; ++ks)
            wb[ks] = *(const bf16x8*)(pw + ks * 32);
        const float bv = b_in[j0 + r];
        PRIO_HI();
        #pragma unroll
        for (int mt = 0; mt < 4; ++mt)
            if (mt < mtc) {
                f32x4 acc = {0.f,0.f,0.f,0.f};
                #pragma unroll
                for (int ks = 0; ks < 4; ++ks)
                    acc = __builtin_amdgcn_mfma_f32_16x16x32_bf16(xa[mt][ks], wb[ks], acc, 0, 0, 0);
                bf16x4 pk = {(bf16)(acc[0]+bv), (bf16)(acc[1]+bv),
                             (bf16)(acc[2]+bv), (bf16)(acc[3]+bv)};
                int rowd = jt * 16 + r;
                int uu = (mt * 2 + qh) ^ (rowd & 7);
                *(bf16x4*)(vT + rowd * 64 + uu * 8 + q1 * 4) = pk;
            }
        PRIO_LO();
    }

    // ---- stage 2 preloads: K A-frags, V^T A-frags (wave-local LDS) ----
    bf16x8 kf[4];
    #pragma unroll
    for (int nt = 0; nt < 4; ++nt)
        if (nt < mtc) {
            int row = nt * 16 + r;
            kf[nt] = *(const bf16x8*)(Kld + row * 32 + (qd ^ (row & 3)) * 8);
        }
    bf16x8 vf[2][2];
    #pragma unroll
    for (int dt = 0; dt < 2; ++dt)
        #pragma unroll
        for (int hk = 0; hk < 2; ++hk) {
            int row = dt * 16 + r;
            vf[dt][hk] = *(const bf16x8*)(vT + row * 64 + ((hk * 4 + qd) ^ (row & 7)) * 8);
        }
    bf16x8 wof[2][4]; float4 bo4[2];
    #pragma unroll
    for (int t2 = 0; t2 < 2; ++t2) {
        const int jg = (h * 2 + t2) * 16;
        const bf16* pw = w_out_b + (size_t)(jg + r) * 128 + qd * 8;
        #pragma unroll
        for (int s = 0; s < 4; ++s)
            wof[t2][s] = *(const bf16x8*)(pw + s * 32);
        bo4[t2] = *(const float4*)(b_out + jg + qd * 4);
    }

    // ---- stage 2: per query-tile mt: S^T -> softmax -> P^T -> PV ----
    #pragma unroll
    for (int mt = 0; mt < 4; ++mt)
        if (mt < mtc) {
            // qf = B-frag Q[agent=r][d=qd*8+jj] from qreg via quad-transform
            i32x2 qa = __builtin_bit_cast(i32x2, qreg[mt][0]);
            i32x2 qb = __builtin_bit_cast(i32x2, qreg[mt][1]);
            i32x4 qw = qtrans(qa[0], qa[1], qb[0], qb[1], qodd);
            bf16x8 qf = __builtin_bit_cast(bf16x8, qw);

            f32x4 S[4];
            PRIO_HI();
            #pragma unroll
            for (int nt = 0; nt < 4; ++nt)
                if (nt < mtc) {
                    f32x4 z = {0.f,0.f,0.f,0.f};
                    S[nt] = __builtin_amdgcn_mfma_f32_16x16x32_bf16(kf[nt], qf, z, 0, 0, 0);
                }
            PRIO_LO();
            // masked softmax (log2 domain; scale pre-folded into Q)
            #pragma unroll
            for (int nt = 0; nt < 4; ++nt) {
                if (nt < mtc) {
                    #pragma unroll
                    for (int i = 0; i < 4; ++i) {
                        bool kv = (nt * 16 + qd * 4 + i) < nb;
                        S[nt][i] = kv ? S[nt][i] : NEG_INF;
                    }
                } else {
                    S[nt] = (f32x4){NEG_INF, NEG_INF, NEG_INF, NEG_INF};
                }
            }
            float tm[4];
            #pragma unroll
            for (int nt = 0; nt < 4; ++nt)
                tm[nt] = fmaxf(fmaxf(S[nt][0], S[nt][1]), fmaxf(S[nt][2], S[nt][3]));
            float mx = fmaxf(fmaxf(tm[0], tm[1]), fmaxf(tm[2], tm[3]));
            mx = fmaxf(mx, __shfl_xor(mx, 16));
            mx = fmaxf(mx, __shfl_xor(mx, 32));
            float lt[4];
            #pragma unroll
            for (int nt = 0; nt < 4; ++nt) {
                float e0 = EXP2(S[nt][0] - mx), e1 = EXP2(S[nt][1] - mx);
                float e2 = EXP2(S[nt][2] - mx), e3 = EXP2(S[nt][3] - mx);
                S[nt][0] = e0; S[nt][1] = e1; S[nt][2] = e2; S[nt][3] = e3;
                lt[nt] = (e0 + e1) + (e2 + e3);
            }
            float l = (lt[0] + lt[1]) + (lt[2] + lt[3]);
            l += __shfl_xor(l, 16);
            l += __shfl_xor(l, 32);
            const float rl = 1.0f / l;
            #pragma unroll
            for (int nt = 0; nt < 4; ++nt)
                #pragma unroll
                for (int i = 0; i < 4; ++i)
                    S[nt][i] *= rl;                       // invalid keys -> exact 0

            // PV: O^T = V^T * P^T ; P^T frags via quad-transform (no bpermute)
            f32x4 o0 = {0.f,0.f,0.f,0.f}, o1 = {0.f,0.f,0.f,0.f};
            #pragma unroll
            for (int hk = 0; hk < 2; ++hk)
                if (hk * 2 < mtc) {
                    int a0 = pk2(S[2*hk  ][0], S[2*hk  ][1]);
                    int a1 = pk2(S[2*hk  ][2], S[2*hk  ][3]);
                    int b0 = pk2(S[2*hk+1][0], S[2*hk+1][1]);
                    int b1 = pk2(S[2*hk+1][2], S[2*hk+1][3]);
                    i32x4 pw4 = qtrans(a0, a1, b0, b1, qodd);
                    bf16x8 pf = __builtin_bit_cast(bf16x8, pw4);
                    PRIO_HI();
                    o0 = __builtin_amdgcn_mfma_f32_16x16x32_bf16(vf[0][hk], pf, o0, 0, 0, 0);
                    o1 = __builtin_amdgcn_mfma_f32_16x16x32_bf16(vf[1][hk], pf, o1, 0, 0, 0);
                    PRIO_LO();
                }

            // ctx^T B-frag via quad-transform -> one b128 LDS write (ctxS
            // overlays K; kf already register-resident; wave-local region)
            {
                int a0 = pk2(o0[0], o0[1]);
                int a1 = pk2(o0[2], o0[3]);
                int b0 = pk2(o1[0], o1[1]);
                int b1 = pk2(o1[2], o1[3]);
                i32x4 cw = qtrans(a0, a1, b0, b1, qodd);
                bf16x8 cf = __builtin_bit_cast(bf16x8, cw);
                *(bf16x8*)(Kld + mt * 512 + lane * 8) = cf;   // ctxS[h][mt][lane]
            }
        }
    __syncthreads();

    // ---- stage 3: out^T = W_out * ctx^T ; float4 stores ----
    #pragma unroll
    for (int mt = 0; mt < 4; ++mt)
        if (mt < mtc) {
            bf16x8 cb[4];
            #pragma unroll
            for (int s = 0; s < 4; ++s)
                cb[s] = *(const bf16x8*)(s_lds + s * 4096 + mt * 512 + lane * 8);
            const int rowa = mt * 16 + r;
            PRIO_HI();
            #pragma unroll
            for (int t2 = 0; t2 < 2; ++t2) {
                f32x4 acc = {0.f,0.f,0.f,0.f};
                #pragma unroll
                for (int s = 0; s < 4; ++s)
                    acc = __builtin_amdgcn_mfma_f32_16x16x32_bf16(wof[t2][s], cb[s], acc, 0, 0, 0);
                if (rowa < nb) {
                    float4 o4 = make_float4(acc[0] + bo4[t2].x, acc[1] + bo4[t2].y,
                                            acc[2] + bo4[t2].z, acc[3] + bo4[t2].w);
                    *(float4*)(out + ((size_t)b * 64 + rowa) * 128
                               + (w * 2 + t2) * 16 + qd * 4) = o4;
                }
            }
            PRIO_LO();
        }

    // ---- zero-fill output rows [nb, 64) -- tail, fire-and-forget ----
    // (disjoint from stage-3's [0,nb) rows; off the kernel front so the
    // stage-1 waitcnt no longer drains these stores)
    {
        const float4 z4 = make_float4(0.f, 0.f, 0.f, 0.f);
        const int nz = (64 - nb) * 32;
        for (int i = tid; i < nz; i += 256) {
            int row = nb + (i >> 5);
            *(float4*)(out + ((size_t)b * 64 + row) * 128 + (i & 31) * 4) = z4;
        }
    }
}

extern "C" void kernel_launch(void* const* d_in, const int* in_sizes, int n_in,
                              void* d_out, int out_size, void* d_ws, size_t ws_size,
                              hipStream_t stream)
{
    const float* att_in = (const float*)d_in[0];
    const float* w_in   = (const float*)d_in[1];
    const float* b_in   = (const float*)d_in[2];
    const float* w_out  = (const float*)d_in[3];
    const float* b_out  = (const float*)d_in[4];
    const int*   agents = (const int*)d_in[5];

    bf16* w_in_b  = (bf16*)d_ws;                         // 49152 * 2B
    bf16* w_out_b = w_in_b + 49152;                      // 16384 * 2B
    int*  offs    = (int*)((char*)d_ws + 131072);        // 2048 * 4B @ 131072
    int*  perm    = nullptr;
    int2* desc    = nullptr;
    if (ws_size >= 139264 + 16384)                       // desc: 2048 * 8B
        desc = (int2*)((char*)d_ws + 139264);
    else if (ws_size >= 139264 + 8192)                   // perm: 2048 * 4B
        perm = (int*)((char*)d_ws + 139264);

    prep_kernel<<<65, 256, 0, stream>>>(w_in, w_out, agents, w_in_b, w_out_b,
                                        offs, perm, desc);
    attn_kernel<<<N_SCENES, 256, 0, stream>>>(att_in, b_in, b_out, w_in_b, w_out_b,
                                              agents, offs, perm, desc,
                                              (float*)d_out);
}